// Round 2
// baseline (2302.202 us; speedup 1.0000x reference)
//
#include <hip/hip_runtime.h>

constexpr int DD = 128;   // hidden dim D
constexpr int AA = 64;    // attention dim A
constexpr int GG = 384;   // 3*D (GRU gates)

#define SLOPE_F 0.22916666666666666f
#define LNEPS   1e-5f

static __device__ __forceinline__ float wave_sum(float v){
#pragma unroll
  for (int off = 32; off > 0; off >>= 1) v += __shfl_xor(v, off, 64);
  return v;
}
static __device__ __forceinline__ float sigm(float x){ return 1.0f / (1.0f + __expf(-x)); }
static __device__ __forceinline__ float rrelu_f(float x){ return x >= 0.0f ? x : SLOPE_F * x; }

// ---- transpose [K,128] -> [128,K] (GRU weights, PyTorch layout -> coalesced)
__global__ void __launch_bounds__(256) k_transpose(const float* __restrict__ w, float* __restrict__ wT, int K){
  int tid = blockIdx.x * blockDim.x + threadIdx.x;
  if (tid < K * DD){
    int k = tid / DD, d = tid - k * DD;
    wT[(size_t)d * K + k] = w[(size_t)k * DD + d];
  }
}

// ---- rel = LN(rel + relu(rel @ rtw + rtb)); one row per wave, in place
__global__ void __launch_bounds__(256) k_rel_transfer(float* __restrict__ rel,
    const float* __restrict__ rtw, const float* __restrict__ rtb,
    const float* __restrict__ g, const float* __restrict__ b, int rows){
  const int lane = threadIdx.x & 63;
  int wave = (int)((blockIdx.x * blockDim.x + threadIdx.x) >> 6);
  if (wave >= rows) return;
  int row = __builtin_amdgcn_readfirstlane(wave);
  const float* x = rel + (size_t)row * DD;
  float y0 = 0.f, y1 = 0.f;
#pragma unroll 4
  for (int d = 0; d < DD; ++d){
    float xd = x[d];
    y0 = fmaf(xd, rtw[d*DD + lane],      y0);
    y1 = fmaf(xd, rtw[d*DD + 64 + lane], y1);
  }
  float t0 = x[lane]      + fmaxf(y0 + rtb[lane],      0.f);
  float t1 = x[64 + lane] + fmaxf(y1 + rtb[64 + lane], 0.f);
  float mu = wave_sum(t0 + t1) * (1.0f/128.0f);
  float e0 = t0 - mu, e1 = t1 - mu;
  float var = wave_sum(e0*e0 + e1*e1) * (1.0f/128.0f);
  float rs = rsqrtf(var + LNEPS);
  float* o = rel + (size_t)row * DD;
  o[lane]      = e0 * rs * g[lane]      + b[lane];
  o[64 + lane] = e1 * rs * g[64 + lane] + b[64 + lane];
}

// ---- in-place LayerNorm of rows
__global__ void __launch_bounds__(256) k_ln_rows(float* __restrict__ X,
    const float* __restrict__ g, const float* __restrict__ b, int rows){
  const int lane = threadIdx.x & 63;
  int wave = (int)((blockIdx.x * blockDim.x + threadIdx.x) >> 6);
  if (wave >= rows) return;
  int row = __builtin_amdgcn_readfirstlane(wave);
  float* x = X + (size_t)row * DD;
  float t0 = x[lane], t1 = x[64 + lane];
  float mu = wave_sum(t0 + t1) * (1.0f/128.0f);
  float e0 = t0 - mu, e1 = t1 - mu;
  float var = wave_sum(e0*e0 + e1*e1) * (1.0f/128.0f);
  float rs = rsqrtf(var + LNEPS);
  x[lane]      = e0 * rs * g[lane]      + b[lane];
  x[64 + lane] = e1 * rs * g[64 + lane] + b[64 + lane];
}

// ---- Y[rows,64] = X[rows,128] @ W[128,64]; 8 rows per wave (weight reuse x8)
// requires rows >= 8; if 8 !| rows, trailing wave re-does overlapping rows (output-only, safe)
__global__ void __launch_bounds__(256) k_proj8(const float* __restrict__ X,
    const float* __restrict__ W, float* __restrict__ Y, int rows){
  const int lane = threadIdx.x & 63;
  int wave = (int)((blockIdx.x * blockDim.x + threadIdx.x) >> 6);
  int r0 = wave * 8;
  if (r0 >= rows) return;
  if (r0 + 8 > rows) r0 = rows - 8;
  r0 = __builtin_amdgcn_readfirstlane(r0);
  const float* xb = X + (size_t)r0 * DD;
  float a[8];
#pragma unroll
  for (int r = 0; r < 8; ++r) a[r] = 0.f;
#pragma unroll 2
  for (int d = 0; d < DD; ++d){
    float w = W[d*AA + lane];
#pragma unroll
    for (int r = 0; r < 8; ++r) a[r] = fmaf(xb[r*DD + d], w, a[r]);
  }
#pragma unroll
  for (int r = 0; r < 8; ++r) Y[(size_t)(r0 + r)*AA + lane] = a[r];
}

// ---- qr[b,:] = rel[q_rel[b]+b*Rp1,:] @ Wqr + bias   (B rows, one per wave)
__global__ void __launch_bounds__(256) k_projq(const float* __restrict__ rel,
    const float* __restrict__ Wqr, const float* __restrict__ bias,
    const int* __restrict__ q_rel, float* __restrict__ out, int Bc, int Rp1){
  const int lane = threadIdx.x & 63;
  int wave = (int)((blockIdx.x * blockDim.x + threadIdx.x) >> 6);
  if (wave >= Bc) return;
  int b = __builtin_amdgcn_readfirstlane(wave);
  int f = __builtin_amdgcn_readfirstlane(q_rel[b] + b * Rp1);
  const float* x = rel + (size_t)f * DD;
  float a = 0.f;
#pragma unroll 4
  for (int d = 0; d < DD; ++d) a = fmaf(x[d], Wqr[d*AA + lane], a);
  out[(size_t)b*AA + lane] = a + bias[lane];
}

// ---- edge kernel: one edge per wave-iter; alpha + scatter-add of msg into agg
__global__ void __launch_bounds__(256) k_edge(const float* __restrict__ hid,
    const float* __restrict__ relE, const float* __restrict__ hsW,
    const float* __restrict__ hrW, const float* __restrict__ qr,
    const float* __restrict__ wal, const float* __restrict__ walb_p,
    const int* __restrict__ sub, const int* __restrict__ obj,
    const int* __restrict__ bidx, const int* __restrict__ reli,
    float* __restrict__ agg, int E, int Rp1){
  const int lane = threadIdx.x & 63;
  const int wpb = blockDim.x >> 6;
  int w0 = blockIdx.x * wpb + (threadIdx.x >> 6);
  const int stride = gridDim.x * wpb;
  const float wa = wal[lane];
  const float wb = walb_p[0];
  for (int e = w0; e < E; e += stride){
    int eu = __builtin_amdgcn_readfirstlane(e);
    int s  = sub[eu];
    int o  = obj[eu];
    int bb = bidx[eu];
    int f  = reli[eu] + bb * Rp1;
    float pre = hsW[(size_t)s*AA + lane] + hrW[(size_t)f*AA + lane] + qr[(size_t)bb*AA + lane];
    float t = rrelu_f(pre);
    float al = sigm(wave_sum(t * wa) + wb);
    // float2 gathers: lane covers dims {2*lane, 2*lane+1}
    const float2* hs2 = (const float2*)(hid  + (size_t)s*DD);
    const float2* hr2 = (const float2*)(relE + (size_t)f*DD);
    float2 hsv = hs2[lane];
    float2 hrv = hr2[lane];
    float m0 = al * (hsv.x + hrv.x);
    float m1 = al * (hsv.y + hrv.y);
    unsafeAtomicAdd(&agg[(size_t)o*DD + 2*lane],     m0);
    unsafeAtomicAdd(&agg[(size_t)o*DD + 2*lane + 1], m1);
  }
}

// ---- X = LN(rrelu(X @ Wm)) ; 8 rows per wave, in-place
__global__ void __launch_bounds__(256) k_wh_ln8(float* __restrict__ X,
    const float* __restrict__ Wm, const float* __restrict__ g,
    const float* __restrict__ b, int rows){
  const int lane = threadIdx.x & 63;
  int wave = (int)((blockIdx.x * blockDim.x + threadIdx.x) >> 6);
  int r0 = wave * 8;
  if (r0 >= rows) return;
  if (r0 + 8 > rows) r0 = rows - 8;
  r0 = __builtin_amdgcn_readfirstlane(r0);
  const float* xb = X + (size_t)r0 * DD;
  float a0[8], a1[8];
#pragma unroll
  for (int r = 0; r < 8; ++r){ a0[r] = 0.f; a1[r] = 0.f; }
#pragma unroll 2
  for (int d = 0; d < DD; ++d){
    float w0 = Wm[d*DD + lane];
    float w1 = Wm[d*DD + 64 + lane];
#pragma unroll
    for (int r = 0; r < 8; ++r){
      float v = xb[r*DD + d];
      a0[r] = fmaf(v, w0, a0[r]);
      a1[r] = fmaf(v, w1, a1[r]);
    }
  }
  float gl = g[lane], gh = g[64+lane], bl = b[lane], bhv = b[64+lane];
#pragma unroll
  for (int r = 0; r < 8; ++r){
    float t0 = rrelu_f(a0[r]);
    float t1 = rrelu_f(a1[r]);
    float mu = wave_sum(t0 + t1) * (1.0f/128.0f);
    float e0 = t0 - mu, e1 = t1 - mu;
    float var = wave_sum(e0*e0 + e1*e1) * (1.0f/128.0f);
    float rs = rsqrtf(var + LNEPS);
    float* o = X + (size_t)(r0 + r) * DD;
    o[lane]      = e0 * rs * gl + bl;
    o[64 + lane] = e1 * rs * gh + bhv;
  }
}

// ---- GRU step: X = gru(x=X, h=H) in-place; 8 rows per wave
template<bool HAS_H>
__global__ void __launch_bounds__(256) k_gru8(float* __restrict__ X,
    const float* __restrict__ H, const float* __restrict__ wihT,
    const float* __restrict__ whhT, const float* __restrict__ bih,
    const float* __restrict__ bhh, int rows){
  const int lane = threadIdx.x & 63;
  int wave = (int)((blockIdx.x * blockDim.x + threadIdx.x) >> 6);
  int r0 = wave * 8;
  if (r0 >= rows) return;
  if (r0 + 8 > rows) r0 = rows - 8;   // rows%8==0 in practice -> no overlap race
  r0 = __builtin_amdgcn_readfirstlane(r0);
  const float* xb = X + (size_t)r0 * DD;
  const float* hb = HAS_H ? (H + (size_t)r0 * DD) : nullptr;
  float ai[8][6], ah[8][6];
#pragma unroll
  for (int r = 0; r < 8; ++r)
#pragma unroll
    for (int m = 0; m < 6; ++m){ ai[r][m] = 0.f; ah[r][m] = 0.f; }

#pragma unroll 2
  for (int d = 0; d < DD; ++d){
    float wi[6];
#pragma unroll
    for (int m = 0; m < 6; ++m) wi[m] = wihT[d*GG + m*64 + lane];
#pragma unroll
    for (int r = 0; r < 8; ++r){
      float xv = xb[r*DD + d];
#pragma unroll
      for (int m = 0; m < 6; ++m) ai[r][m] = fmaf(xv, wi[m], ai[r][m]);
    }
    if (HAS_H){
      float wh[6];
#pragma unroll
      for (int m = 0; m < 6; ++m) wh[m] = whhT[d*GG + m*64 + lane];
#pragma unroll
      for (int r = 0; r < 8; ++r){
        float hv = hb[r*DD + d];
#pragma unroll
        for (int m = 0; m < 6; ++m) ah[r][m] = fmaf(hv, wh[m], ah[r][m]);
      }
    }
  }
  float bi[6], bh2[6];
#pragma unroll
  for (int m = 0; m < 6; ++m){ bi[m] = bih[m*64 + lane]; bh2[m] = bhh[m*64 + lane]; }
#pragma unroll
  for (int r = 0; r < 8; ++r){
#pragma unroll
    for (int hf = 0; hf < 2; ++hf){
      float gir = ai[r][hf]   + bi[hf];
      float giz = ai[r][2+hf] + bi[2+hf];
      float gin = ai[r][4+hf] + bi[4+hf];
      float ghr = (HAS_H ? ah[r][hf]   : 0.f) + bh2[hf];
      float ghz = (HAS_H ? ah[r][2+hf] : 0.f) + bh2[2+hf];
      float ghn = (HAS_H ? ah[r][4+hf] : 0.f) + bh2[4+hf];
      float rg = sigm(gir + ghr);
      float zg = sigm(giz + ghz);
      float ng = tanhf(gin + rg * ghn);
      float hp = HAS_H ? H[(size_t)(r0 + r) * DD + hf*64 + lane] : 0.f;
      X[(size_t)(r0 + r) * DD + hf*64 + lane] = (1.f - zg) * ng + zg * hp;
    }
  }
}

// ---- scores = H @ wf ; record max-index winner per (batch,ent) slot
__global__ void __launch_bounds__(256) k_score(const float* __restrict__ Hf,
    const float* __restrict__ wf, const int* __restrict__ nb, const int* __restrict__ ne,
    float* __restrict__ scores, int* __restrict__ winner, int rows, int NENT){
  const int lane = threadIdx.x & 63;
  int wave = (int)((blockIdx.x * blockDim.x + threadIdx.x) >> 6);
  if (wave >= rows) return;
  int row = __builtin_amdgcn_readfirstlane(wave);
  float v = Hf[(size_t)row*DD + lane] * wf[lane] + Hf[(size_t)row*DD + 64 + lane] * wf[64 + lane];
  float s = wave_sum(v);
  if (lane == 0){
    scores[row] = s;
    int slot = nb[row] * NENT + ne[row];
    atomicMax(&winner[slot], row);
  }
}

__global__ void __launch_bounds__(256) k_scatter(const float* __restrict__ scores,
    const int* __restrict__ winner, const int* __restrict__ nb, const int* __restrict__ ne,
    float* __restrict__ out, int rows, int NENT){
  int n = blockIdx.x * blockDim.x + threadIdx.x;
  if (n < rows){
    int slot = nb[n] * NENT + ne[n];
    if (winner[slot] == n) out[slot] = scores[n];
  }
}

extern "C" void kernel_launch(void* const* d_in, const int* in_sizes, int n_in,
                              void* d_out, int out_size, void* d_ws, size_t ws_size,
                              hipStream_t stream){
  const float* hidden0 = (const float*)d_in[0];
  const float* rel0    = (const float*)d_in[1];
  const int* batch_idx = (const int*)d_in[2];
  const int* rel_i     = (const int*)d_in[3];
  const int* sub       = (const int*)d_in[4];
  const int* obj       = (const int*)d_in[5];
  const int* q_rel     = (const int*)d_in[6];
  const int* nb        = (const int*)d_in[7];
  const int* ne        = (const int*)d_in[8];
  const float* Ws      = (const float*)d_in[9];
  const float* Wr      = (const float*)d_in[10];
  const float* Wqr_w   = (const float*)d_in[11];
  const float* Wqr_b   = (const float*)d_in[12];
  const float* Wal_w   = (const float*)d_in[13];
  const float* Wal_b   = (const float*)d_in[14];
  const float* Wh      = (const float*)d_in[15];
  const float* rt_w    = (const float*)d_in[16];
  const float* rt_b    = (const float*)d_in[17];
  const float* ln_g    = (const float*)d_in[18];
  const float* ln_b    = (const float*)d_in[19];
  const float* lnr_g   = (const float*)d_in[20];
  const float* lnr_b   = (const float*)d_in[21];
  const float* wih     = (const float*)d_in[22];
  const float* whh     = (const float*)d_in[23];
  const float* bih     = (const float*)d_in[24];
  const float* bhh     = (const float*)d_in[25];
  const float* wfin    = (const float*)d_in[26];

  const int N    = in_sizes[0] / DD;
  const int NR   = in_sizes[1] / DD;
  const int E    = in_sizes[2];
  const int Bc   = in_sizes[6];
  const int L    = in_sizes[14];
  const int Rp1  = NR / Bc;
  const int NENT = out_size / Bc;

  char* wsp = (char*)d_ws;
  auto alloc = [&](size_t bytes) -> void* {
    void* p = (void*)wsp;
    wsp += (bytes + 255) & ~(size_t)255;
    return p;
  };
  float* BUF0    = (float*)alloc((size_t)N * DD * 4);
  float* BUF1    = (float*)alloc((size_t)N * DD * 4);
  float* rel_cur = (float*)alloc((size_t)NR * DD * 4);
  float* hsW     = (float*)alloc((size_t)N * AA * 4);
  float* hrW     = (float*)alloc((size_t)NR * AA * 4);
  float* qr      = (float*)alloc((size_t)Bc * AA * 4);
  float* wihT    = (float*)alloc((size_t)GG * DD * 4);
  float* whhT    = (float*)alloc((size_t)GG * DD * 4);
  float* scores  = (float*)alloc((size_t)N * 4);
  int*   winner  = (int*)alloc((size_t)Bc * NENT * 4);
  (void)ws_size; (void)n_in;

  hipMemcpyAsync(rel_cur, rel0, (size_t)NR * DD * 4, hipMemcpyDeviceToDevice, stream);
  k_transpose<<<(GG*DD + 255)/256, 256, 0, stream>>>(wih, wihT, GG);
  k_transpose<<<(GG*DD + 255)/256, 256, 0, stream>>>(whh, whhT, GG);
  hipMemsetAsync(d_out, 0, (size_t)out_size * 4, stream);
  hipMemsetAsync(winner, 0xFF, (size_t)Bc * NENT * 4, stream);

  const float* hid_in = hidden0;
  auto blocks4 = [](int waves){ return (waves + 3) / 4; };  // 4 waves per 256-thr block

  for (int i = 0; i < L; ++i){
    float* agg = (i & 1) ? BUF1 : BUF0;
    const float* hid_prev = (i == 0) ? nullptr : ((i & 1) ? BUF0 : BUF1);
    k_rel_transfer<<<blocks4(NR), 256, 0, stream>>>(rel_cur,
        rt_w + (size_t)i*DD*DD, rt_b + (size_t)i*DD,
        lnr_g + (size_t)i*DD, lnr_b + (size_t)i*DD, NR);
    k_proj8<<<blocks4((N+7)/8), 256, 0, stream>>>(hid_in, Ws + (size_t)i*DD*AA, hsW, N);
    k_proj8<<<blocks4((NR+7)/8), 256, 0, stream>>>(rel_cur, Wr + (size_t)i*DD*AA, hrW, NR);
    k_projq<<<blocks4(Bc), 256, 0, stream>>>(rel_cur, Wqr_w + (size_t)i*DD*AA,
        Wqr_b + (size_t)i*AA, q_rel, qr, Bc, Rp1);
    hipMemsetAsync(agg, 0, (size_t)N * DD * 4, stream);
    k_edge<<<8192, 256, 0, stream>>>(hid_in, rel_cur, hsW, hrW, qr,
        Wal_w + (size_t)i*AA, Wal_b + i,
        sub, obj, batch_idx, rel_i, agg, E, Rp1);
    k_wh_ln8<<<blocks4((N+7)/8), 256, 0, stream>>>(agg, Wh + (size_t)i*DD*DD,
        ln_g + (size_t)i*DD, ln_b + (size_t)i*DD, N);
    if (i == 0)
      k_gru8<false><<<blocks4((N+7)/8), 256, 0, stream>>>(agg, nullptr, wihT, whhT, bih, bhh, N);
    else
      k_gru8<true><<<blocks4((N+7)/8), 256, 0, stream>>>(agg, hid_prev, wihT, whhT, bih, bhh, N);
    k_ln_rows<<<blocks4(NR), 256, 0, stream>>>(rel_cur,
        lnr_g + (size_t)i*DD, lnr_b + (size_t)i*DD, NR);
    hid_in = agg;
  }

  k_score<<<blocks4(N), 256, 0, stream>>>(hid_in, wfin, nb, ne, scores, winner, N, NENT);
  k_scatter<<<(N + 255)/256, 256, 0, stream>>>(scores, winner, nb, ne, (float*)d_out, N, NENT);
}

// Round 3
// 1442.792 us; speedup vs baseline: 1.5957x; 1.5957x over previous
//
#include <hip/hip_runtime.h>
#include <hip/hip_bf16.h>

constexpr int DD = 128;   // hidden dim D
constexpr int AA = 64;    // attention dim A
constexpr int GG = 384;   // 3*D (GRU gates)

#define SLOPE_F 0.22916666666666666f
#define LNEPS   1e-5f

typedef __attribute__((ext_vector_type(8))) short short8;
typedef __attribute__((ext_vector_type(4))) float f32x4;

static __device__ __forceinline__ float wave_sum(float v){
#pragma unroll
  for (int off = 32; off > 0; off >>= 1) v += __shfl_xor(v, off, 64);
  return v;
}
static __device__ __forceinline__ float sigm(float x){ return 1.0f / (1.0f + __expf(-x)); }
static __device__ __forceinline__ float rrelu_f(float x){ return x >= 0.0f ? x : SLOPE_F * x; }
static __device__ __forceinline__ short bf16b(float f){
  __hip_bfloat16 h = __float2bfloat16(f);
  return *reinterpret_cast<short*>(&h);
}

// ---- rel = LN(rel + relu(rel @ rtw + rtb)); one row per wave, in place
__global__ void __launch_bounds__(256) k_rel_transfer(float* __restrict__ rel,
    const float* __restrict__ rtw, const float* __restrict__ rtb,
    const float* __restrict__ g, const float* __restrict__ b, int rows){
  const int lane = threadIdx.x & 63;
  int wave = (int)((blockIdx.x * blockDim.x + threadIdx.x) >> 6);
  if (wave >= rows) return;
  int row = __builtin_amdgcn_readfirstlane(wave);
  const float* x = rel + (size_t)row * DD;
  float y0 = 0.f, y1 = 0.f;
#pragma unroll 4
  for (int d = 0; d < DD; ++d){
    float xd = x[d];
    y0 = fmaf(xd, rtw[d*DD + lane],      y0);
    y1 = fmaf(xd, rtw[d*DD + 64 + lane], y1);
  }
  float t0 = x[lane]      + fmaxf(y0 + rtb[lane],      0.f);
  float t1 = x[64 + lane] + fmaxf(y1 + rtb[64 + lane], 0.f);
  float mu = wave_sum(t0 + t1) * (1.0f/128.0f);
  float e0 = t0 - mu, e1 = t1 - mu;
  float var = wave_sum(e0*e0 + e1*e1) * (1.0f/128.0f);
  float rs = rsqrtf(var + LNEPS);
  float* o = rel + (size_t)row * DD;
  o[lane]      = e0 * rs * g[lane]      + b[lane];
  o[64 + lane] = e1 * rs * g[64 + lane] + b[64 + lane];
}

// ---- in-place LayerNorm of rows
__global__ void __launch_bounds__(256) k_ln_rows(float* __restrict__ X,
    const float* __restrict__ g, const float* __restrict__ b, int rows){
  const int lane = threadIdx.x & 63;
  int wave = (int)((blockIdx.x * blockDim.x + threadIdx.x) >> 6);
  if (wave >= rows) return;
  int row = __builtin_amdgcn_readfirstlane(wave);
  float* x = X + (size_t)row * DD;
  float t0 = x[lane], t1 = x[64 + lane];
  float mu = wave_sum(t0 + t1) * (1.0f/128.0f);
  float e0 = t0 - mu, e1 = t1 - mu;
  float var = wave_sum(e0*e0 + e1*e1) * (1.0f/128.0f);
  float rs = rsqrtf(var + LNEPS);
  x[lane]      = e0 * rs * g[lane]      + b[lane];
  x[64 + lane] = e1 * rs * g[64 + lane] + b[64 + lane];
}

// ---- Y[rows,64] = X[rows,128] @ W[128,64]; 8 rows per wave
__global__ void __launch_bounds__(256) k_proj8(const float* __restrict__ X,
    const float* __restrict__ W, float* __restrict__ Y, int rows){
  const int lane = threadIdx.x & 63;
  int wave = (int)((blockIdx.x * blockDim.x + threadIdx.x) >> 6);
  int r0 = wave * 8;
  if (r0 >= rows) return;
  if (r0 + 8 > rows) r0 = rows - 8;
  r0 = __builtin_amdgcn_readfirstlane(r0);
  const float* xb = X + (size_t)r0 * DD;
  float a[8];
#pragma unroll
  for (int r = 0; r < 8; ++r) a[r] = 0.f;
#pragma unroll 2
  for (int d = 0; d < DD; ++d){
    float w = W[d*AA + lane];
#pragma unroll
    for (int r = 0; r < 8; ++r) a[r] = fmaf(xb[r*DD + d], w, a[r]);
  }
#pragma unroll
  for (int r = 0; r < 8; ++r) Y[(size_t)(r0 + r)*AA + lane] = a[r];
}

// ---- qr[b,:] = rel[q_rel[b]+b*Rp1,:] @ Wqr + bias
__global__ void __launch_bounds__(256) k_projq(const float* __restrict__ rel,
    const float* __restrict__ Wqr, const float* __restrict__ bias,
    const int* __restrict__ q_rel, float* __restrict__ out, int Bc, int Rp1){
  const int lane = threadIdx.x & 63;
  int wave = (int)((blockIdx.x * blockDim.x + threadIdx.x) >> 6);
  if (wave >= Bc) return;
  int b = __builtin_amdgcn_readfirstlane(wave);
  int f = __builtin_amdgcn_readfirstlane(q_rel[b] + b * Rp1);
  const float* x = rel + (size_t)f * DD;
  float a = 0.f;
#pragma unroll 4
  for (int d = 0; d < DD; ++d) a = fmaf(x[d], Wqr[d*AA + lane], a);
  out[(size_t)b*AA + lane] = a + bias[lane];
}

// ---- edge kernel (ROUND-1 contiguous pattern: lane & 64+lane, dense atomics)
__global__ void __launch_bounds__(256) k_edge(const float* __restrict__ hid,
    const float* __restrict__ relE, const float* __restrict__ hsW,
    const float* __restrict__ hrW, const float* __restrict__ qr,
    const float* __restrict__ wal, const float* __restrict__ walb_p,
    const int* __restrict__ sub, const int* __restrict__ obj,
    const int* __restrict__ bidx, const int* __restrict__ reli,
    float* __restrict__ agg, int E, int Rp1){
  const int lane = threadIdx.x & 63;
  const int wpb = blockDim.x >> 6;
  int w0 = blockIdx.x * wpb + (threadIdx.x >> 6);
  const int stride = gridDim.x * wpb;
  const float wa = wal[lane];
  const float wb = walb_p[0];
  for (int e = w0; e < E; e += stride){
    int eu = __builtin_amdgcn_readfirstlane(e);
    int s  = sub[eu];
    int o  = obj[eu];
    int bb = bidx[eu];
    int f  = reli[eu] + bb * Rp1;
    float pre = hsW[(size_t)s*AA + lane] + hrW[(size_t)f*AA + lane] + qr[(size_t)bb*AA + lane];
    float t = rrelu_f(pre);
    float al = sigm(wave_sum(t * wa) + wb);
    float hs0 = hid[(size_t)s*DD + lane],  hs1 = hid[(size_t)s*DD + 64 + lane];
    float hr0 = relE[(size_t)f*DD + lane], hr1 = relE[(size_t)f*DD + 64 + lane];
    unsafeAtomicAdd(&agg[(size_t)o*DD + lane],      al * (hs0 + hr0));
    unsafeAtomicAdd(&agg[(size_t)o*DD + 64 + lane], al * (hs1 + hr1));
  }
}

// ---- X = LN(rrelu(X @ Wm)) ; 8 rows per wave, in-place
__global__ void __launch_bounds__(256) k_wh_ln8(float* __restrict__ X,
    const float* __restrict__ Wm, const float* __restrict__ g,
    const float* __restrict__ b, int rows){
  const int lane = threadIdx.x & 63;
  int wave = (int)((blockIdx.x * blockDim.x + threadIdx.x) >> 6);
  int r0 = wave * 8;
  if (r0 >= rows) return;
  if (r0 + 8 > rows) r0 = rows - 8;
  r0 = __builtin_amdgcn_readfirstlane(r0);
  const float* xb = X + (size_t)r0 * DD;
  float a0[8], a1[8];
#pragma unroll
  for (int r = 0; r < 8; ++r){ a0[r] = 0.f; a1[r] = 0.f; }
#pragma unroll 2
  for (int d = 0; d < DD; ++d){
    float w0 = Wm[d*DD + lane];
    float w1 = Wm[d*DD + 64 + lane];
#pragma unroll
    for (int r = 0; r < 8; ++r){
      float v = xb[r*DD + d];
      a0[r] = fmaf(v, w0, a0[r]);
      a1[r] = fmaf(v, w1, a1[r]);
    }
  }
  float gl = g[lane], gh = g[64+lane], bl = b[lane], bhv = b[64+lane];
#pragma unroll
  for (int r = 0; r < 8; ++r){
    float t0 = rrelu_f(a0[r]);
    float t1 = rrelu_f(a1[r]);
    float mu = wave_sum(t0 + t1) * (1.0f/128.0f);
    float e0 = t0 - mu, e1 = t1 - mu;
    float var = wave_sum(e0*e0 + e1*e1) * (1.0f/128.0f);
    float rs = rsqrtf(var + LNEPS);
    float* o = X + (size_t)(r0 + r) * DD;
    o[lane]      = e0 * rs * gl + bl;
    o[64 + lane] = e1 * rs * gh + bhv;
  }
}

// ---- pre-swizzle GRU weight W[Nc,128] (PyTorch [3D,D]) into MFMA B-fragment order, bf16.
// fragment (ctile, ks, lane) holds 8 bf16: B[k][c] = W[c][k], k=ks*32+(lane>>4)*8+j, c=ctile*16+(lane&15)
__global__ void __launch_bounds__(256) k_prep_bfrag(const float* __restrict__ W,
    short* __restrict__ out, int Nc){
  int idx = blockIdx.x * blockDim.x + threadIdx.x;
  int total = (Nc >> 4) * 4 * 64;
  if (idx >= total) return;
  int lane = idx & 63, ks = (idx >> 6) & 3, ct = idx >> 8;
  int k = ks*32 + ((lane >> 4) << 3);
  int c = (ct << 4) + (lane & 15);
  const float* src = W + (size_t)c * DD + k;
  short8 v;
#pragma unroll
  for (int j = 0; j < 8; ++j) v[j] = bf16b(src[j]);
  *reinterpret_cast<short8*>(out + (size_t)idx * 8) = v;
}

// ---- fused MFMA GRU: H = gru(x=X, h=H) in place. One wave = 32 rows x 16 cols.
// A-frags (X,H rows) cvt f32->bf16 on the fly; B pre-swizzled (k_prep_bfrag).
// In-place H is race-free: each wave reads/writes only its own 32 rows.
// C/D layout (m89-verified): row=(lane>>4)*4+reg, col=lane&15.
template<bool HAS_H>
__global__ void __launch_bounds__(256) k_gru_mfma(const float* __restrict__ X,
    float* H, const short* __restrict__ Bih, const short* __restrict__ Bhh,
    const float* __restrict__ bih, const float* __restrict__ bhh, int rows){
  const int lane = threadIdx.x & 63;
  int wave = (int)((blockIdx.x * blockDim.x + threadIdx.x) >> 6);
  const int nrt = (rows + 31) >> 5;           // 32-row tiles
  int rt = wave >> 3;                          // row-tile
  int ct = wave & 7;                           // col-tile within D (8 x 16)
  if (rt >= nrt) return;
  int r0 = rt * 32;
  if (r0 + 32 > rows) r0 = rows - 32;          // rows%32==0 in practice (100000)
  r0 = __builtin_amdgcn_readfirstlane(r0);
  const int arow = lane & 15;                  // A-frag row within tile
  const int koff = (lane >> 4) << 3;           // A-frag k offset within 32-chunk

  // load + convert A fragments for X (and H)
  short8 ax[2][4], ah8[2][4];
#pragma unroll
  for (int rr = 0; rr < 2; ++rr){
#pragma unroll
    for (int ks = 0; ks < 4; ++ks){
      const float* p = X + (size_t)(r0 + rr*16 + arow) * DD + ks*32 + koff;
      float4 f0 = *(const float4*)p;
      float4 f1 = *(const float4*)(p + 4);
      short8 v;
      v[0]=bf16b(f0.x); v[1]=bf16b(f0.y); v[2]=bf16b(f0.z); v[3]=bf16b(f0.w);
      v[4]=bf16b(f1.x); v[5]=bf16b(f1.y); v[6]=bf16b(f1.z); v[7]=bf16b(f1.w);
      ax[rr][ks] = v;
      if (HAS_H){
        const float* q = H + (size_t)(r0 + rr*16 + arow) * DD + ks*32 + koff;
        float4 g0 = *(const float4*)q;
        float4 g1 = *(const float4*)(q + 4);
        short8 u;
        u[0]=bf16b(g0.x); u[1]=bf16b(g0.y); u[2]=bf16b(g0.z); u[3]=bf16b(g0.w);
        u[4]=bf16b(g1.x); u[5]=bf16b(g1.y); u[6]=bf16b(g1.z); u[7]=bf16b(g1.w);
        ah8[rr][ks] = u;
      }
    }
  }

  f32x4 ai[2][3], ahg[2][3];
#pragma unroll
  for (int rr = 0; rr < 2; ++rr)
#pragma unroll
    for (int g = 0; g < 3; ++g){ ai[rr][g] = (f32x4)0.f; ahg[rr][g] = (f32x4)0.f; }

#pragma unroll
  for (int g = 0; g < 3; ++g){
    const int gt = g*8 + ct;                   // absolute col-tile in [0,24)
#pragma unroll
    for (int ks = 0; ks < 4; ++ks){
      short8 bw = *reinterpret_cast<const short8*>(Bih + ((size_t)(gt*4 + ks)*64 + lane)*8);
      ai[0][g] = __builtin_amdgcn_mfma_f32_16x16x32_bf16(ax[0][ks], bw, ai[0][g], 0, 0, 0);
      ai[1][g] = __builtin_amdgcn_mfma_f32_16x16x32_bf16(ax[1][ks], bw, ai[1][g], 0, 0, 0);
      if (HAS_H){
        short8 bw2 = *reinterpret_cast<const short8*>(Bhh + ((size_t)(gt*4 + ks)*64 + lane)*8);
        ahg[0][g] = __builtin_amdgcn_mfma_f32_16x16x32_bf16(ah8[0][ks], bw2, ahg[0][g], 0, 0, 0);
        ahg[1][g] = __builtin_amdgcn_mfma_f32_16x16x32_bf16(ah8[1][ks], bw2, ahg[1][g], 0, 0, 0);
      }
    }
  }

  const int col = ct*16 + (lane & 15);         // output col in [0,128)
  const float bi_r = bih[col], bi_z = bih[128 + col], bi_n = bih[256 + col];
  const float bh_r = bhh[col], bh_z = bhh[128 + col], bh_n = bhh[256 + col];
#pragma unroll
  for (int rr = 0; rr < 2; ++rr){
#pragma unroll
    for (int reg = 0; reg < 4; ++reg){
      int row = r0 + rr*16 + ((lane >> 4) << 2) + reg;
      float gi_r = ai[rr][0][reg] + bi_r;
      float gi_z = ai[rr][1][reg] + bi_z;
      float gi_n = ai[rr][2][reg] + bi_n;
      float gh_r = (HAS_H ? ahg[rr][0][reg] : 0.f) + bh_r;
      float gh_z = (HAS_H ? ahg[rr][1][reg] : 0.f) + bh_z;
      float gh_n = (HAS_H ? ahg[rr][2][reg] : 0.f) + bh_n;
      float rg = sigm(gi_r + gh_r);
      float zg = sigm(gi_z + gh_z);
      float ng = tanhf(gi_n + rg * gh_n);
      float hp = HAS_H ? H[(size_t)row * DD + col] : 0.f;
      H[(size_t)row * DD + col] = (1.f - zg) * ng + zg * hp;
    }
  }
}

// ---- scores = H @ wf ; record max-index winner per (batch,ent) slot
__global__ void __launch_bounds__(256) k_score(const float* __restrict__ Hf,
    const float* __restrict__ wf, const int* __restrict__ nb, const int* __restrict__ ne,
    float* __restrict__ scores, int* __restrict__ winner, int rows, int NENT){
  const int lane = threadIdx.x & 63;
  int wave = (int)((blockIdx.x * blockDim.x + threadIdx.x) >> 6);
  if (wave >= rows) return;
  int row = __builtin_amdgcn_readfirstlane(wave);
  float v = Hf[(size_t)row*DD + lane] * wf[lane] + Hf[(size_t)row*DD + 64 + lane] * wf[64 + lane];
  float s = wave_sum(v);
  if (lane == 0){
    scores[row] = s;
    int slot = nb[row] * NENT + ne[row];
    atomicMax(&winner[slot], row);
  }
}

__global__ void __launch_bounds__(256) k_scatter(const float* __restrict__ scores,
    const int* __restrict__ winner, const int* __restrict__ nb, const int* __restrict__ ne,
    float* __restrict__ out, int rows, int NENT){
  int n = blockIdx.x * blockDim.x + threadIdx.x;
  if (n < rows){
    int slot = nb[n] * NENT + ne[n];
    if (winner[slot] == n) out[slot] = scores[n];
  }
}

extern "C" void kernel_launch(void* const* d_in, const int* in_sizes, int n_in,
                              void* d_out, int out_size, void* d_ws, size_t ws_size,
                              hipStream_t stream){
  const float* hidden0 = (const float*)d_in[0];
  const float* rel0    = (const float*)d_in[1];
  const int* batch_idx = (const int*)d_in[2];
  const int* rel_i     = (const int*)d_in[3];
  const int* sub       = (const int*)d_in[4];
  const int* obj       = (const int*)d_in[5];
  const int* q_rel     = (const int*)d_in[6];
  const int* nb        = (const int*)d_in[7];
  const int* ne        = (const int*)d_in[8];
  const float* Ws      = (const float*)d_in[9];
  const float* Wr      = (const float*)d_in[10];
  const float* Wqr_w   = (const float*)d_in[11];
  const float* Wqr_b   = (const float*)d_in[12];
  const float* Wal_w   = (const float*)d_in[13];
  const float* Wal_b   = (const float*)d_in[14];
  const float* Wh      = (const float*)d_in[15];
  const float* rt_w    = (const float*)d_in[16];
  const float* rt_b    = (const float*)d_in[17];
  const float* ln_g    = (const float*)d_in[18];
  const float* ln_b    = (const float*)d_in[19];
  const float* lnr_g   = (const float*)d_in[20];
  const float* lnr_b   = (const float*)d_in[21];
  const float* wih     = (const float*)d_in[22];
  const float* whh     = (const float*)d_in[23];
  const float* bih     = (const float*)d_in[24];
  const float* bhh     = (const float*)d_in[25];
  const float* wfin    = (const float*)d_in[26];

  const int N    = in_sizes[0] / DD;
  const int NR   = in_sizes[1] / DD;
  const int E    = in_sizes[2];
  const int Bc   = in_sizes[6];
  const int L    = in_sizes[14];
  const int Rp1  = NR / Bc;
  const int NENT = out_size / Bc;

  char* wsp = (char*)d_ws;
  auto alloc = [&](size_t bytes) -> void* {
    void* p = (void*)wsp;
    wsp += (bytes + 255) & ~(size_t)255;
    return p;
  };
  float* AGG     = (float*)alloc((size_t)N * DD * 4);   // per-layer aggregation / x
  float* HBUF    = (float*)alloc((size_t)N * DD * 4);   // persistent hidden state
  float* rel_cur = (float*)alloc((size_t)NR * DD * 4);
  float* hsW     = (float*)alloc((size_t)N * AA * 4);
  float* hrW     = (float*)alloc((size_t)NR * AA * 4);
  float* qr      = (float*)alloc((size_t)Bc * AA * 4);
  short* Bih     = (short*)alloc((size_t)(GG/16) * 4 * 64 * 8 * 2);
  short* Bhh     = (short*)alloc((size_t)(GG/16) * 4 * 64 * 8 * 2);
  float* scores  = (float*)alloc((size_t)N * 4);
  int*   winner  = (int*)alloc((size_t)Bc * NENT * 4);
  (void)ws_size; (void)n_in;

  hipMemcpyAsync(rel_cur, rel0, (size_t)NR * DD * 4, hipMemcpyDeviceToDevice, stream);
  {
    int total = (GG/16) * 4 * 64;
    k_prep_bfrag<<<(total + 255)/256, 256, 0, stream>>>(wih, Bih, GG);
    k_prep_bfrag<<<(total + 255)/256, 256, 0, stream>>>(whh, Bhh, GG);
  }
  hipMemsetAsync(d_out, 0, (size_t)out_size * 4, stream);
  hipMemsetAsync(winner, 0xFF, (size_t)Bc * NENT * 4, stream);

  const float* hid_in = hidden0;
  auto blocks4 = [](int waves){ return (waves + 3) / 4; };  // 4 waves per 256-thr block

  for (int i = 0; i < L; ++i){
    k_rel_transfer<<<blocks4(NR), 256, 0, stream>>>(rel_cur,
        rt_w + (size_t)i*DD*DD, rt_b + (size_t)i*DD,
        lnr_g + (size_t)i*DD, lnr_b + (size_t)i*DD, NR);
    k_proj8<<<blocks4((N+7)/8), 256, 0, stream>>>(hid_in, Ws + (size_t)i*DD*AA, hsW, N);
    k_proj8<<<blocks4((NR+7)/8), 256, 0, stream>>>(rel_cur, Wr + (size_t)i*DD*AA, hrW, NR);
    k_projq<<<blocks4(Bc), 256, 0, stream>>>(rel_cur, Wqr_w + (size_t)i*DD*AA,
        Wqr_b + (size_t)i*AA, q_rel, qr, Bc, Rp1);
    hipMemsetAsync(AGG, 0, (size_t)N * DD * 4, stream);
    k_edge<<<8192, 256, 0, stream>>>(hid_in, rel_cur, hsW, hrW, qr,
        Wal_w + (size_t)i*AA, Wal_b + i,
        sub, obj, batch_idx, rel_i, AGG, E, Rp1);
    k_wh_ln8<<<blocks4((N+7)/8), 256, 0, stream>>>(AGG, Wh + (size_t)i*DD*DD,
        ln_g + (size_t)i*DD, ln_b + (size_t)i*DD, N);
    {
      int waves = ((N + 31)/32) * 8;
      if (i == 0)
        k_gru_mfma<false><<<blocks4(waves), 256, 0, stream>>>(AGG, HBUF, Bih, Bhh, bih, bhh, N);
      else
        k_gru_mfma<true><<<blocks4(waves), 256, 0, stream>>>(AGG, HBUF, Bih, Bhh, bih, bhh, N);
    }
    k_ln_rows<<<blocks4(NR), 256, 0, stream>>>(rel_cur,
        lnr_g + (size_t)i*DD, lnr_b + (size_t)i*DD, NR);
    hid_in = HBUF;
  }

  k_score<<<blocks4(N), 256, 0, stream>>>(hid_in, wfin, nb, ne, scores, winner, N, NENT);
  k_scatter<<<(N + 255)/256, 256, 0, stream>>>(scores, winner, nb, ne, (float*)d_out, N, NENT);
}

// Round 4
// 1123.952 us; speedup vs baseline: 2.0483x; 1.2837x over previous
//
#include <hip/hip_runtime.h>
#include <hip/hip_bf16.h>

constexpr int DD = 128;   // hidden dim D
constexpr int AA = 64;    // attention dim A
constexpr int GG = 384;   // 3*D (GRU gates)

#define SLOPE_F 0.22916666666666666f
#define LNEPS   1e-5f

typedef __attribute__((ext_vector_type(8))) short short8;
typedef __attribute__((ext_vector_type(4))) float f32x4;

static __device__ __forceinline__ float wave_sum(float v){
#pragma unroll
  for (int off = 32; off > 0; off >>= 1) v += __shfl_xor(v, off, 64);
  return v;
}
static __device__ __forceinline__ float sigm(float x){ return 1.0f / (1.0f + __expf(-x)); }
static __device__ __forceinline__ float rrelu_f(float x){ return x >= 0.0f ? x : SLOPE_F * x; }
static __device__ __forceinline__ short bf16b(float f){
  __hip_bfloat16 h = __float2bfloat16(f);
  return *reinterpret_cast<short*>(&h);
}

// ---- rel = LN(rel + relu(rel @ rtw + rtb)); one row per wave, in place
__global__ void __launch_bounds__(256) k_rel_transfer(float* __restrict__ rel,
    const float* __restrict__ rtw, const float* __restrict__ rtb,
    const float* __restrict__ g, const float* __restrict__ b, int rows){
  const int lane = threadIdx.x & 63;
  int wave = (int)((blockIdx.x * blockDim.x + threadIdx.x) >> 6);
  if (wave >= rows) return;
  int row = __builtin_amdgcn_readfirstlane(wave);
  const float* x = rel + (size_t)row * DD;
  float y0 = 0.f, y1 = 0.f;
#pragma unroll 4
  for (int d = 0; d < DD; ++d){
    float xd = x[d];
    y0 = fmaf(xd, rtw[d*DD + lane],      y0);
    y1 = fmaf(xd, rtw[d*DD + 64 + lane], y1);
  }
  float t0 = x[lane]      + fmaxf(y0 + rtb[lane],      0.f);
  float t1 = x[64 + lane] + fmaxf(y1 + rtb[64 + lane], 0.f);
  float mu = wave_sum(t0 + t1) * (1.0f/128.0f);
  float e0 = t0 - mu, e1 = t1 - mu;
  float var = wave_sum(e0*e0 + e1*e1) * (1.0f/128.0f);
  float rs = rsqrtf(var + LNEPS);
  float* o = rel + (size_t)row * DD;
  o[lane]      = e0 * rs * g[lane]      + b[lane];
  o[64 + lane] = e1 * rs * g[64 + lane] + b[64 + lane];
}

// ---- in-place LayerNorm of rows
__global__ void __launch_bounds__(256) k_ln_rows(float* __restrict__ X,
    const float* __restrict__ g, const float* __restrict__ b, int rows){
  const int lane = threadIdx.x & 63;
  int wave = (int)((blockIdx.x * blockDim.x + threadIdx.x) >> 6);
  if (wave >= rows) return;
  int row = __builtin_amdgcn_readfirstlane(wave);
  float* x = X + (size_t)row * DD;
  float t0 = x[lane], t1 = x[64 + lane];
  float mu = wave_sum(t0 + t1) * (1.0f/128.0f);
  float e0 = t0 - mu, e1 = t1 - mu;
  float var = wave_sum(e0*e0 + e1*e1) * (1.0f/128.0f);
  float rs = rsqrtf(var + LNEPS);
  x[lane]      = e0 * rs * g[lane]      + b[lane];
  x[64 + lane] = e1 * rs * g[64 + lane] + b[64 + lane];
}

// ---- Y[rows,64] = X[rows,128] @ W[128,64]; 8 rows per wave
__global__ void __launch_bounds__(256) k_proj8(const float* __restrict__ X,
    const float* __restrict__ W, float* __restrict__ Y, int rows){
  const int lane = threadIdx.x & 63;
  int wave = (int)((blockIdx.x * blockDim.x + threadIdx.x) >> 6);
  int r0 = wave * 8;
  if (r0 >= rows) return;
  if (r0 + 8 > rows) r0 = rows - 8;
  r0 = __builtin_amdgcn_readfirstlane(r0);
  const float* xb = X + (size_t)r0 * DD;
  float a[8];
#pragma unroll
  for (int r = 0; r < 8; ++r) a[r] = 0.f;
#pragma unroll 2
  for (int d = 0; d < DD; ++d){
    float w = W[d*AA + lane];
#pragma unroll
    for (int r = 0; r < 8; ++r) a[r] = fmaf(xb[r*DD + d], w, a[r]);
  }
#pragma unroll
  for (int r = 0; r < 8; ++r) Y[(size_t)(r0 + r)*AA + lane] = a[r];
}

// ---- qr[b,:] = rel[q_rel[b]+b*Rp1,:] @ Wqr + bias
__global__ void __launch_bounds__(256) k_projq(const float* __restrict__ rel,
    const float* __restrict__ Wqr, const float* __restrict__ bias,
    const int* __restrict__ q_rel, float* __restrict__ out, int Bc, int Rp1){
  const int lane = threadIdx.x & 63;
  int wave = (int)((blockIdx.x * blockDim.x + threadIdx.x) >> 6);
  if (wave >= Bc) return;
  int b = __builtin_amdgcn_readfirstlane(wave);
  int f = __builtin_amdgcn_readfirstlane(q_rel[b] + b * Rp1);
  const float* x = rel + (size_t)f * DD;
  float a = 0.f;
#pragma unroll 4
  for (int d = 0; d < DD; ++d) a = fmaf(x[d], Wqr[d*AA + lane], a);
  out[(size_t)b*AA + lane] = a + bias[lane];
}

// ================= CSR build (once per call; obj constant across layers) ====
__global__ void __launch_bounds__(256) k_hist(const int* __restrict__ obj, int* __restrict__ deg, int E){
  int idx = blockIdx.x * blockDim.x + threadIdx.x;
  if (idx < E) atomicAdd(&deg[obj[idx]], 1);
}

// block-local exclusive scan (1024 elems/block); bsum[b] = block total
__global__ void __launch_bounds__(1024) k_scan1(const int* __restrict__ deg,
    int* __restrict__ row_start, int* __restrict__ bsum, int n){
  __shared__ int sm[1024];
  int t = threadIdx.x;
  int i = blockIdx.x * 1024 + t;
  int v = (i < n) ? deg[i] : 0;
  sm[t] = v; __syncthreads();
#pragma unroll
  for (int off = 1; off < 1024; off <<= 1){
    int x = (t >= off) ? sm[t - off] : 0;
    __syncthreads();
    sm[t] += x;
    __syncthreads();
  }
  if (i < n) row_start[i] = sm[t] - v;       // exclusive
  if (t == 1023) bsum[blockIdx.x] = sm[1023];
}

// single-block exclusive scan of block sums
__global__ void __launch_bounds__(1024) k_scan2(int* __restrict__ bsum, int nb){
  __shared__ int sm[1024];
  int t = threadIdx.x;
  int v = (t < nb) ? bsum[t] : 0;
  sm[t] = v; __syncthreads();
#pragma unroll
  for (int off = 1; off < 1024; off <<= 1){
    int x = (t >= off) ? sm[t - off] : 0;
    __syncthreads();
    sm[t] += x;
    __syncthreads();
  }
  if (t < nb) bsum[t] = sm[t] - v;           // exclusive
}

__global__ void __launch_bounds__(256) k_scan3(int* __restrict__ row_start,
    const int* __restrict__ bsum, int n, int E){
  int i = blockIdx.x * blockDim.x + threadIdx.x;
  if (i < n) row_start[i] += bsum[i >> 10];
  if (i == 0) row_start[n] = E;
}

__global__ void __launch_bounds__(256) k_scatter_edges(const int* __restrict__ obj,
    const int* __restrict__ row_start, int* __restrict__ cursor,
    int* __restrict__ perm, int E){
  int e = blockIdx.x * blockDim.x + threadIdx.x;
  if (e < E){
    int o = obj[e];
    int pos = row_start[o] + atomicAdd(&cursor[o], 1);
    perm[pos] = e;
  }
}

// ---- CSR edge kernel: one wave per node; no atomics, agg written exactly once
__global__ void __launch_bounds__(256) k_edge_csr(const float* __restrict__ hid,
    const float* __restrict__ relE, const float* __restrict__ hsW,
    const float* __restrict__ hrW, const float* __restrict__ qr,
    const float* __restrict__ wal, const float* __restrict__ walb_p,
    const int* __restrict__ sub, const int* __restrict__ bidx,
    const int* __restrict__ reli, const int* __restrict__ row_start,
    const int* __restrict__ perm, float* __restrict__ agg, int Nn, int Rp1){
  const int lane = threadIdx.x & 63;
  int wave = (int)((blockIdx.x * blockDim.x + threadIdx.x) >> 6);
  if (wave >= Nn) return;
  int o = __builtin_amdgcn_readfirstlane(wave);
  const int s0 = __builtin_amdgcn_readfirstlane(row_start[o]);
  const int s1 = __builtin_amdgcn_readfirstlane(row_start[o + 1]);
  const float wa = wal[lane];
  const float wb = walb_p[0];
  float acc0 = 0.f, acc1 = 0.f;
  for (int base = s0; base < s1; base += 64){
    int cnt = s1 - base; if (cnt > 64) cnt = 64;
    int jj = base + lane;
    int ev = (jj < s1) ? perm[jj] : 0;         // parallel index gather, one edge/lane
    int sv = sub[ev];
    int bv = bidx[ev];
    int fv = reli[ev] + bv * Rp1;
    for (int k = 0; k < cnt; ++k){
      int s  = __shfl(sv, k);
      int f  = __shfl(fv, k);
      int bb = __shfl(bv, k);
      float pre = hsW[(size_t)s*AA + lane] + hrW[(size_t)f*AA + lane] + qr[(size_t)bb*AA + lane];
      float t = rrelu_f(pre);
      float al = sigm(wave_sum(t * wa) + wb);
      acc0 = fmaf(al, hid[(size_t)s*DD + lane]      + relE[(size_t)f*DD + lane],      acc0);
      acc1 = fmaf(al, hid[(size_t)s*DD + 64 + lane] + relE[(size_t)f*DD + 64 + lane], acc1);
    }
  }
  agg[(size_t)o*DD + lane]      = acc0;
  agg[(size_t)o*DD + 64 + lane] = acc1;
}

// ---- X = LN(rrelu(X @ Wm)) ; 8 rows per wave, in-place
__global__ void __launch_bounds__(256) k_wh_ln8(float* __restrict__ X,
    const float* __restrict__ Wm, const float* __restrict__ g,
    const float* __restrict__ b, int rows){
  const int lane = threadIdx.x & 63;
  int wave = (int)((blockIdx.x * blockDim.x + threadIdx.x) >> 6);
  int r0 = wave * 8;
  if (r0 >= rows) return;
  if (r0 + 8 > rows) r0 = rows - 8;
  r0 = __builtin_amdgcn_readfirstlane(r0);
  const float* xb = X + (size_t)r0 * DD;
  float a0[8], a1[8];
#pragma unroll
  for (int r = 0; r < 8; ++r){ a0[r] = 0.f; a1[r] = 0.f; }
#pragma unroll 2
  for (int d = 0; d < DD; ++d){
    float w0 = Wm[d*DD + lane];
    float w1 = Wm[d*DD + 64 + lane];
#pragma unroll
    for (int r = 0; r < 8; ++r){
      float v = xb[r*DD + d];
      a0[r] = fmaf(v, w0, a0[r]);
      a1[r] = fmaf(v, w1, a1[r]);
    }
  }
  float gl = g[lane], gh = g[64+lane], bl = b[lane], bhv = b[64+lane];
#pragma unroll
  for (int r = 0; r < 8; ++r){
    float t0 = rrelu_f(a0[r]);
    float t1 = rrelu_f(a1[r]);
    float mu = wave_sum(t0 + t1) * (1.0f/128.0f);
    float e0 = t0 - mu, e1 = t1 - mu;
    float var = wave_sum(e0*e0 + e1*e1) * (1.0f/128.0f);
    float rs = rsqrtf(var + LNEPS);
    float* o = X + (size_t)(r0 + r) * DD;
    o[lane]      = e0 * rs * gl + bl;
    o[64 + lane] = e1 * rs * gh + bhv;
  }
}

// ---- pre-swizzle GRU weight W[Nc,128] into MFMA B-fragment order, bf16
__global__ void __launch_bounds__(256) k_prep_bfrag(const float* __restrict__ W,
    short* __restrict__ out, int Nc){
  int idx = blockIdx.x * blockDim.x + threadIdx.x;
  int total = (Nc >> 4) * 4 * 64;
  if (idx >= total) return;
  int lane = idx & 63, ks = (idx >> 6) & 3, ct = idx >> 8;
  int k = ks*32 + ((lane >> 4) << 3);
  int c = (ct << 4) + (lane & 15);
  const float* src = W + (size_t)c * DD + k;
  short8 v;
#pragma unroll
  for (int j = 0; j < 8; ++j) v[j] = bf16b(src[j]);
  *reinterpret_cast<short8*>(out + (size_t)idx * 8) = v;
}

// ---- fused MFMA GRU: H = gru(x=X, h=H) in place. One wave = 32 rows x 16 cols.
template<bool HAS_H>
__global__ void __launch_bounds__(256) k_gru_mfma(const float* __restrict__ X,
    float* H, const short* __restrict__ Bih, const short* __restrict__ Bhh,
    const float* __restrict__ bih, const float* __restrict__ bhh, int rows){
  const int lane = threadIdx.x & 63;
  int wave = (int)((blockIdx.x * blockDim.x + threadIdx.x) >> 6);
  const int nrt = (rows + 31) >> 5;
  int rt = wave >> 3;
  int ct = wave & 7;
  if (rt >= nrt) return;
  int r0 = rt * 32;
  if (r0 + 32 > rows) r0 = rows - 32;
  r0 = __builtin_amdgcn_readfirstlane(r0);
  const int arow = lane & 15;
  const int koff = (lane >> 4) << 3;

  short8 ax[2][4], ah8[2][4];
#pragma unroll
  for (int rr = 0; rr < 2; ++rr){
#pragma unroll
    for (int ks = 0; ks < 4; ++ks){
      const float* p = X + (size_t)(r0 + rr*16 + arow) * DD + ks*32 + koff;
      float4 f0 = *(const float4*)p;
      float4 f1 = *(const float4*)(p + 4);
      short8 v;
      v[0]=bf16b(f0.x); v[1]=bf16b(f0.y); v[2]=bf16b(f0.z); v[3]=bf16b(f0.w);
      v[4]=bf16b(f1.x); v[5]=bf16b(f1.y); v[6]=bf16b(f1.z); v[7]=bf16b(f1.w);
      ax[rr][ks] = v;
      if (HAS_H){
        const float* q = H + (size_t)(r0 + rr*16 + arow) * DD + ks*32 + koff;
        float4 g0 = *(const float4*)q;
        float4 g1 = *(const float4*)(q + 4);
        short8 u;
        u[0]=bf16b(g0.x); u[1]=bf16b(g0.y); u[2]=bf16b(g0.z); u[3]=bf16b(g0.w);
        u[4]=bf16b(g1.x); u[5]=bf16b(g1.y); u[6]=bf16b(g1.z); u[7]=bf16b(g1.w);
        ah8[rr][ks] = u;
      }
    }
  }

  f32x4 ai[2][3], ahg[2][3];
#pragma unroll
  for (int rr = 0; rr < 2; ++rr)
#pragma unroll
    for (int g = 0; g < 3; ++g){ ai[rr][g] = (f32x4)0.f; ahg[rr][g] = (f32x4)0.f; }

#pragma unroll
  for (int g = 0; g < 3; ++g){
    const int gt = g*8 + ct;
#pragma unroll
    for (int ks = 0; ks < 4; ++ks){
      short8 bw = *reinterpret_cast<const short8*>(Bih + ((size_t)(gt*4 + ks)*64 + lane)*8);
      ai[0][g] = __builtin_amdgcn_mfma_f32_16x16x32_bf16(ax[0][ks], bw, ai[0][g], 0, 0, 0);
      ai[1][g] = __builtin_amdgcn_mfma_f32_16x16x32_bf16(ax[1][ks], bw, ai[1][g], 0, 0, 0);
      if (HAS_H){
        short8 bw2 = *reinterpret_cast<const short8*>(Bhh + ((size_t)(gt*4 + ks)*64 + lane)*8);
        ahg[0][g] = __builtin_amdgcn_mfma_f32_16x16x32_bf16(ah8[0][ks], bw2, ahg[0][g], 0, 0, 0);
        ahg[1][g] = __builtin_amdgcn_mfma_f32_16x16x32_bf16(ah8[1][ks], bw2, ahg[1][g], 0, 0, 0);
      }
    }
  }

  const int col = ct*16 + (lane & 15);
  const float bi_r = bih[col], bi_z = bih[128 + col], bi_n = bih[256 + col];
  const float bh_r = bhh[col], bh_z = bhh[128 + col], bh_n = bhh[256 + col];
#pragma unroll
  for (int rr = 0; rr < 2; ++rr){
#pragma unroll
    for (int reg = 0; reg < 4; ++reg){
      int row = r0 + rr*16 + ((lane >> 4) << 2) + reg;
      float gi_r = ai[rr][0][reg] + bi_r;
      float gi_z = ai[rr][1][reg] + bi_z;
      float gi_n = ai[rr][2][reg] + bi_n;
      float gh_r = (HAS_H ? ahg[rr][0][reg] : 0.f) + bh_r;
      float gh_z = (HAS_H ? ahg[rr][1][reg] : 0.f) + bh_z;
      float gh_n = (HAS_H ? ahg[rr][2][reg] : 0.f) + bh_n;
      float rg = sigm(gi_r + gh_r);
      float zg = sigm(gi_z + gh_z);
      float ng = tanhf(gi_n + rg * gh_n);
      float hp = HAS_H ? H[(size_t)row * DD + col] : 0.f;
      H[(size_t)row * DD + col] = (1.f - zg) * ng + zg * hp;
    }
  }
}

// ---- scores = H @ wf ; record max-index winner per (batch,ent) slot
__global__ void __launch_bounds__(256) k_score(const float* __restrict__ Hf,
    const float* __restrict__ wf, const int* __restrict__ nb, const int* __restrict__ ne,
    float* __restrict__ scores, int* __restrict__ winner, int rows, int NENT){
  const int lane = threadIdx.x & 63;
  int wave = (int)((blockIdx.x * blockDim.x + threadIdx.x) >> 6);
  if (wave >= rows) return;
  int row = __builtin_amdgcn_readfirstlane(wave);
  float v = Hf[(size_t)row*DD + lane] * wf[lane] + Hf[(size_t)row*DD + 64 + lane] * wf[64 + lane];
  float s = wave_sum(v);
  if (lane == 0){
    scores[row] = s;
    int slot = nb[row] * NENT + ne[row];
    atomicMax(&winner[slot], row);
  }
}

__global__ void __launch_bounds__(256) k_scatter(const float* __restrict__ scores,
    const int* __restrict__ winner, const int* __restrict__ nb, const int* __restrict__ ne,
    float* __restrict__ out, int rows, int NENT){
  int n = blockIdx.x * blockDim.x + threadIdx.x;
  if (n < rows){
    int slot = nb[n] * NENT + ne[n];
    if (winner[slot] == n) out[slot] = scores[n];
  }
}

extern "C" void kernel_launch(void* const* d_in, const int* in_sizes, int n_in,
                              void* d_out, int out_size, void* d_ws, size_t ws_size,
                              hipStream_t stream){
  const float* hidden0 = (const float*)d_in[0];
  const float* rel0    = (const float*)d_in[1];
  const int* batch_idx = (const int*)d_in[2];
  const int* rel_i     = (const int*)d_in[3];
  const int* sub       = (const int*)d_in[4];
  const int* obj       = (const int*)d_in[5];
  const int* q_rel     = (const int*)d_in[6];
  const int* nb        = (const int*)d_in[7];
  const int* ne        = (const int*)d_in[8];
  const float* Ws      = (const float*)d_in[9];
  const float* Wr      = (const float*)d_in[10];
  const float* Wqr_w   = (const float*)d_in[11];
  const float* Wqr_b   = (const float*)d_in[12];
  const float* Wal_w   = (const float*)d_in[13];
  const float* Wal_b   = (const float*)d_in[14];
  const float* Wh      = (const float*)d_in[15];
  const float* rt_w    = (const float*)d_in[16];
  const float* rt_b    = (const float*)d_in[17];
  const float* ln_g    = (const float*)d_in[18];
  const float* ln_b    = (const float*)d_in[19];
  const float* lnr_g   = (const float*)d_in[20];
  const float* lnr_b   = (const float*)d_in[21];
  const float* wih     = (const float*)d_in[22];
  const float* whh     = (const float*)d_in[23];
  const float* bih     = (const float*)d_in[24];
  const float* bhh     = (const float*)d_in[25];
  const float* wfin    = (const float*)d_in[26];

  const int N    = in_sizes[0] / DD;
  const int NR   = in_sizes[1] / DD;
  const int E    = in_sizes[2];
  const int Bc   = in_sizes[6];
  const int L    = in_sizes[14];
  const int Rp1  = NR / Bc;
  const int NENT = out_size / Bc;

  char* wsp = (char*)d_ws;
  auto alloc = [&](size_t bytes) -> void* {
    void* p = (void*)wsp;
    wsp += (bytes + 255) & ~(size_t)255;
    return p;
  };
  float* AGG     = (float*)alloc((size_t)N * DD * 4);
  float* HBUF    = (float*)alloc((size_t)N * DD * 4);
  float* rel_cur = (float*)alloc((size_t)NR * DD * 4);
  float* hsW     = (float*)alloc((size_t)N * AA * 4);
  float* hrW     = (float*)alloc((size_t)NR * AA * 4);
  float* qr      = (float*)alloc((size_t)Bc * AA * 4);
  short* Bih     = (short*)alloc((size_t)(GG/16) * 4 * 64 * 8 * 2);
  short* Bhh     = (short*)alloc((size_t)(GG/16) * 4 * 64 * 8 * 2);
  float* scores  = (float*)alloc((size_t)N * 4);
  int*   winner  = (int*)alloc((size_t)Bc * NENT * 4);
  int*   deg     = (int*)alloc((size_t)N * 4);
  int*   row_st  = (int*)alloc((size_t)(N + 1) * 4);
  int*   cursor  = (int*)alloc((size_t)N * 4);
  int*   perm    = (int*)alloc((size_t)E * 4);
  int*   bsum    = (int*)alloc((size_t)1024 * 4);
  (void)ws_size; (void)n_in;

  hipMemcpyAsync(rel_cur, rel0, (size_t)NR * DD * 4, hipMemcpyDeviceToDevice, stream);
  {
    int total = (GG/16) * 4 * 64;
    k_prep_bfrag<<<(total + 255)/256, 256, 0, stream>>>(wih, Bih, GG);
    k_prep_bfrag<<<(total + 255)/256, 256, 0, stream>>>(whh, Bhh, GG);
  }
  hipMemsetAsync(d_out, 0, (size_t)out_size * 4, stream);
  hipMemsetAsync(winner, 0xFF, (size_t)Bc * NENT * 4, stream);

  // ---- build CSR over obj (edges constant across layers)
  hipMemsetAsync(deg, 0, (size_t)N * 4, stream);
  hipMemsetAsync(cursor, 0, (size_t)N * 4, stream);
  k_hist<<<(E + 255)/256, 256, 0, stream>>>(obj, deg, E);
  {
    int nb1 = (N + 1023)/1024;
    k_scan1<<<nb1, 1024, 0, stream>>>(deg, row_st, bsum, N);
    k_scan2<<<1, 1024, 0, stream>>>(bsum, nb1);
    k_scan3<<<(N + 255)/256, 256, 0, stream>>>(row_st, bsum, N, E);
  }
  k_scatter_edges<<<(E + 255)/256, 256, 0, stream>>>(obj, row_st, cursor, perm, E);

  const float* hid_in = hidden0;
  auto blocks4 = [](int waves){ return (waves + 3) / 4; };

  for (int i = 0; i < L; ++i){
    k_rel_transfer<<<blocks4(NR), 256, 0, stream>>>(rel_cur,
        rt_w + (size_t)i*DD*DD, rt_b + (size_t)i*DD,
        lnr_g + (size_t)i*DD, lnr_b + (size_t)i*DD, NR);
    k_proj8<<<blocks4((N+7)/8), 256, 0, stream>>>(hid_in, Ws + (size_t)i*DD*AA, hsW, N);
    k_proj8<<<blocks4((NR+7)/8), 256, 0, stream>>>(rel_cur, Wr + (size_t)i*DD*AA, hrW, NR);
    k_projq<<<blocks4(Bc), 256, 0, stream>>>(rel_cur, Wqr_w + (size_t)i*DD*AA,
        Wqr_b + (size_t)i*AA, q_rel, qr, Bc, Rp1);
    k_edge_csr<<<blocks4(N), 256, 0, stream>>>(hid_in, rel_cur, hsW, hrW, qr,
        Wal_w + (size_t)i*AA, Wal_b + i,
        sub, batch_idx, rel_i, row_st, perm, AGG, N, Rp1);
    k_wh_ln8<<<blocks4((N+7)/8), 256, 0, stream>>>(AGG, Wh + (size_t)i*DD*DD,
        ln_g + (size_t)i*DD, ln_b + (size_t)i*DD, N);
    {
      int waves = ((N + 31)/32) * 8;
      if (i == 0)
        k_gru_mfma<false><<<blocks4(waves), 256, 0, stream>>>(AGG, HBUF, Bih, Bhh, bih, bhh, N);
      else
        k_gru_mfma<true><<<blocks4(waves), 256, 0, stream>>>(AGG, HBUF, Bih, Bhh, bih, bhh, N);
    }
    k_ln_rows<<<blocks4(NR), 256, 0, stream>>>(rel_cur,
        lnr_g + (size_t)i*DD, lnr_b + (size_t)i*DD, NR);
    hid_in = HBUF;
  }

  k_score<<<blocks4(N), 256, 0, stream>>>(hid_in, wfin, nb, ne, scores, winner, N, NENT);
  k_scatter<<<(N + 255)/256, 256, 0, stream>>>(scores, winner, nb, ne, (float*)d_out, N, NENT);
}

// Round 5
// 656.535 us; speedup vs baseline: 3.5066x; 1.7119x over previous
//
#include <hip/hip_runtime.h>
#include <hip/hip_bf16.h>

constexpr int DD = 128;   // hidden dim D
constexpr int AA = 64;    // attention dim A
constexpr int GG = 384;   // 3*D (GRU gates)
constexpr int XPAD = 136; // LDS X-tile row stride in shorts (128 + 8 pad)

#define SLOPE_F 0.22916666666666666f
#define LNEPS   1e-5f

typedef __attribute__((ext_vector_type(8))) short short8;
typedef __attribute__((ext_vector_type(4))) float f32x4;

static __device__ __forceinline__ float wave_sum(float v){
#pragma unroll
  for (int off = 32; off > 0; off >>= 1) v += __shfl_xor(v, off, 64);
  return v;
}
static __device__ __forceinline__ float red16(float v){
#pragma unroll
  for (int off = 1; off < 16; off <<= 1) v += __shfl_xor(v, off, 64);
  return v;
}
static __device__ __forceinline__ float sigm(float x){ return 1.0f / (1.0f + __expf(-x)); }
static __device__ __forceinline__ float rrelu_f(float x){ return x >= 0.0f ? x : SLOPE_F * x; }
static __device__ __forceinline__ short bf16b(float f){
  __hip_bfloat16 h = __float2bfloat16(f);
  return *reinterpret_cast<short*>(&h);
}
static __device__ __forceinline__ short8 ld_frag_f32(const float* p){
  float4 f0 = *(const float4*)p;
  float4 f1 = *(const float4*)(p + 4);
  short8 v;
  v[0]=bf16b(f0.x); v[1]=bf16b(f0.y); v[2]=bf16b(f0.z); v[3]=bf16b(f0.w);
  v[4]=bf16b(f1.x); v[5]=bf16b(f1.y); v[6]=bf16b(f1.z); v[7]=bf16b(f1.w);
  return v;
}

// ---- rel = LN(rel + relu(rel @ rtw + rtb)); one row per wave, in place
__global__ void __launch_bounds__(256) k_rel_transfer(float* __restrict__ rel,
    const float* __restrict__ rtw, const float* __restrict__ rtb,
    const float* __restrict__ g, const float* __restrict__ b, int rows){
  const int lane = threadIdx.x & 63;
  int wave = (int)((blockIdx.x * blockDim.x + threadIdx.x) >> 6);
  if (wave >= rows) return;
  int row = __builtin_amdgcn_readfirstlane(wave);
  const float* x = rel + (size_t)row * DD;
  float y0 = 0.f, y1 = 0.f;
#pragma unroll 4
  for (int d = 0; d < DD; ++d){
    float xd = x[d];
    y0 = fmaf(xd, rtw[d*DD + lane],      y0);
    y1 = fmaf(xd, rtw[d*DD + 64 + lane], y1);
  }
  float t0 = x[lane]      + fmaxf(y0 + rtb[lane],      0.f);
  float t1 = x[64 + lane] + fmaxf(y1 + rtb[64 + lane], 0.f);
  float mu = wave_sum(t0 + t1) * (1.0f/128.0f);
  float e0 = t0 - mu, e1 = t1 - mu;
  float var = wave_sum(e0*e0 + e1*e1) * (1.0f/128.0f);
  float rs = rsqrtf(var + LNEPS);
  float* o = rel + (size_t)row * DD;
  o[lane]      = e0 * rs * g[lane]      + b[lane];
  o[64 + lane] = e1 * rs * g[64 + lane] + b[64 + lane];
}

// ---- in-place LayerNorm of rows
__global__ void __launch_bounds__(256) k_ln_rows(float* __restrict__ X,
    const float* __restrict__ g, const float* __restrict__ b, int rows){
  const int lane = threadIdx.x & 63;
  int wave = (int)((blockIdx.x * blockDim.x + threadIdx.x) >> 6);
  if (wave >= rows) return;
  int row = __builtin_amdgcn_readfirstlane(wave);
  float* x = X + (size_t)row * DD;
  float t0 = x[lane], t1 = x[64 + lane];
  float mu = wave_sum(t0 + t1) * (1.0f/128.0f);
  float e0 = t0 - mu, e1 = t1 - mu;
  float var = wave_sum(e0*e0 + e1*e1) * (1.0f/128.0f);
  float rs = rsqrtf(var + LNEPS);
  x[lane]      = e0 * rs * g[lane]      + b[lane];
  x[64 + lane] = e1 * rs * g[64 + lane] + b[64 + lane];
}

// ---- prep bf16 B-fragments from k-major weight W[K=128][C] (ldc = C)
// frag (ct,ks,lane,j) = W[(ks*32+(lane>>4)*8+j)*ldc + ct*16+(lane&15)]
__global__ void __launch_bounds__(256) k_prep_bfrag_km(const float* __restrict__ W,
    short* __restrict__ out, int C, int ldc){
  int idx = blockIdx.x * blockDim.x + threadIdx.x;
  int total = (C >> 4) * 4 * 64;
  if (idx >= total) return;
  int lane = idx & 63, ks = (idx >> 6) & 3, ct = idx >> 8;
  int k = ks*32 + ((lane >> 4) << 3);
  int c = (ct << 4) + (lane & 15);
  short8 v;
#pragma unroll
  for (int j = 0; j < 8; ++j) v[j] = bf16b(W[(size_t)(k + j)*ldc + c]);
  *reinterpret_cast<short8*>(out + (size_t)idx * 8) = v;
}

// ---- prep bf16 B-fragments from c-major weight W[Nc][128] (PyTorch [out,in])
__global__ void __launch_bounds__(256) k_prep_bfrag(const float* __restrict__ W,
    short* __restrict__ out, int Nc){
  int idx = blockIdx.x * blockDim.x + threadIdx.x;
  int total = (Nc >> 4) * 4 * 64;
  if (idx >= total) return;
  int lane = idx & 63, ks = (idx >> 6) & 3, ct = idx >> 8;
  int k = ks*32 + ((lane >> 4) << 3);
  int c = (ct << 4) + (lane & 15);
  const float* src = W + (size_t)c * DD + k;
  short8 v;
#pragma unroll
  for (int j = 0; j < 8; ++j) v[j] = bf16b(src[j]);
  *reinterpret_cast<short8*>(out + (size_t)idx * 8) = v;
}

// ---- MFMA projection: Y[rows,64] = X[rows,128] @ W ; one wave = 16 rows x 64 cols
__global__ void __launch_bounds__(256) k_proj_mfma(const float* __restrict__ X,
    const short* __restrict__ Bf, float* __restrict__ Y, int rows){
  const int lane = threadIdx.x & 63;
  int wave = (int)((blockIdx.x * blockDim.x + threadIdx.x) >> 6);
  int r0 = wave * 16;
  if (r0 >= rows) return;
  if (r0 + 16 > rows) r0 = rows - 16;   // output-only overlap, safe
  r0 = __builtin_amdgcn_readfirstlane(r0);
  const int arow = lane & 15;
  const int koff = (lane >> 4) << 3;
  short8 ax[4];
#pragma unroll
  for (int ks = 0; ks < 4; ++ks)
    ax[ks] = ld_frag_f32(X + (size_t)(r0 + arow) * DD + ks*32 + koff);
  f32x4 acc[4];
#pragma unroll
  for (int ct = 0; ct < 4; ++ct){
    acc[ct] = (f32x4)0.f;
#pragma unroll
    for (int ks = 0; ks < 4; ++ks){
      short8 bw = *reinterpret_cast<const short8*>(Bf + ((size_t)(ct*4 + ks)*64 + lane)*8);
      acc[ct] = __builtin_amdgcn_mfma_f32_16x16x32_bf16(ax[ks], bw, acc[ct], 0, 0, 0);
    }
  }
#pragma unroll
  for (int ct = 0; ct < 4; ++ct){
    int col = ct*16 + (lane & 15);
#pragma unroll
    for (int reg = 0; reg < 4; ++reg){
      int row = r0 + ((lane >> 4) << 2) + reg;
      Y[(size_t)row*AA + col] = acc[ct][reg];
    }
  }
}

// ---- qr[b,:] = rel[q_rel[b]+b*Rp1,:] @ Wqr + bias
__global__ void __launch_bounds__(256) k_projq(const float* __restrict__ rel,
    const float* __restrict__ Wqr, const float* __restrict__ bias,
    const int* __restrict__ q_rel, float* __restrict__ out, int Bc, int Rp1){
  const int lane = threadIdx.x & 63;
  int wave = (int)((blockIdx.x * blockDim.x + threadIdx.x) >> 6);
  if (wave >= Bc) return;
  int b = __builtin_amdgcn_readfirstlane(wave);
  int f = __builtin_amdgcn_readfirstlane(q_rel[b] + b * Rp1);
  const float* x = rel + (size_t)f * DD;
  float a = 0.f;
#pragma unroll 4
  for (int d = 0; d < DD; ++d) a = fmaf(x[d], Wqr[d*AA + lane], a);
  out[(size_t)b*AA + lane] = a + bias[lane];
}

// ================= CSR build (once per call; obj constant across layers) ====
__global__ void __launch_bounds__(256) k_hist(const int* __restrict__ obj, int* __restrict__ deg, int E){
  int idx = blockIdx.x * blockDim.x + threadIdx.x;
  if (idx < E) atomicAdd(&deg[obj[idx]], 1);
}

__global__ void __launch_bounds__(1024) k_scan1(const int* __restrict__ deg,
    int* __restrict__ row_start, int* __restrict__ bsum, int n){
  __shared__ int sm[1024];
  int t = threadIdx.x;
  int i = blockIdx.x * 1024 + t;
  int v = (i < n) ? deg[i] : 0;
  sm[t] = v; __syncthreads();
#pragma unroll
  for (int off = 1; off < 1024; off <<= 1){
    int x = (t >= off) ? sm[t - off] : 0;
    __syncthreads();
    sm[t] += x;
    __syncthreads();
  }
  if (i < n) row_start[i] = sm[t] - v;
  if (t == 1023) bsum[blockIdx.x] = sm[1023];
}

__global__ void __launch_bounds__(1024) k_scan2(int* __restrict__ bsum, int nb){
  __shared__ int sm[1024];
  int t = threadIdx.x;
  int v = (t < nb) ? bsum[t] : 0;
  sm[t] = v; __syncthreads();
#pragma unroll
  for (int off = 1; off < 1024; off <<= 1){
    int x = (t >= off) ? sm[t - off] : 0;
    __syncthreads();
    sm[t] += x;
    __syncthreads();
  }
  if (t < nb) bsum[t] = sm[t] - v;
}

__global__ void __launch_bounds__(256) k_scan3(int* __restrict__ row_start,
    const int* __restrict__ bsum, int n, int E){
  int i = blockIdx.x * blockDim.x + threadIdx.x;
  if (i < n) row_start[i] += bsum[i >> 10];
  if (i == 0) row_start[n] = E;
}

__global__ void __launch_bounds__(256) k_scatter_edges(const int* __restrict__ obj,
    const int* __restrict__ row_start, int* __restrict__ cursor,
    int* __restrict__ perm, int E){
  int e = blockIdx.x * blockDim.x + threadIdx.x;
  if (e < E){
    int o = obj[e];
    int pos = row_start[o] + atomicAdd(&cursor[o], 1);
    perm[pos] = e;
  }
}

// ---- CSR edge kernel: one wave per node; no atomics, agg written exactly once
__global__ void __launch_bounds__(256) k_edge_csr(const float* __restrict__ hid,
    const float* __restrict__ relE, const float* __restrict__ hsW,
    const float* __restrict__ hrW, const float* __restrict__ qr,
    const float* __restrict__ wal, const float* __restrict__ walb_p,
    const int* __restrict__ sub, const int* __restrict__ bidx,
    const int* __restrict__ reli, const int* __restrict__ row_start,
    const int* __restrict__ perm, float* __restrict__ agg, int Nn, int Rp1){
  const int lane = threadIdx.x & 63;
  int wave = (int)((blockIdx.x * blockDim.x + threadIdx.x) >> 6);
  if (wave >= Nn) return;
  int o = __builtin_amdgcn_readfirstlane(wave);
  const int s0 = __builtin_amdgcn_readfirstlane(row_start[o]);
  const int s1 = __builtin_amdgcn_readfirstlane(row_start[o + 1]);
  const float wa = wal[lane];
  const float wb = walb_p[0];
  float acc0 = 0.f, acc1 = 0.f;
  for (int base = s0; base < s1; base += 64){
    int cnt = s1 - base; if (cnt > 64) cnt = 64;
    int jj = base + lane;
    int ev = (jj < s1) ? perm[jj] : 0;
    int sv = sub[ev];
    int bv = bidx[ev];
    int fv = reli[ev] + bv * Rp1;
    for (int k = 0; k < cnt; ++k){
      int s  = __shfl(sv, k);
      int f  = __shfl(fv, k);
      int bb = __shfl(bv, k);
      float pre = hsW[(size_t)s*AA + lane] + hrW[(size_t)f*AA + lane] + qr[(size_t)bb*AA + lane];
      float t = rrelu_f(pre);
      float al = sigm(wave_sum(t * wa) + wb);
      acc0 = fmaf(al, hid[(size_t)s*DD + lane]      + relE[(size_t)f*DD + lane],      acc0);
      acc1 = fmaf(al, hid[(size_t)s*DD + 64 + lane] + relE[(size_t)f*DD + 64 + lane], acc1);
    }
  }
  agg[(size_t)o*DD + lane]      = acc0;
  agg[(size_t)o*DD + 64 + lane] = acc1;
}

// ---- FUSED: H = gru(x = LN(rrelu(AGG@Wh)), h = H), in place.
// One wave owns 16 rows x all 128 cols. Phase1: Wh-GEMM + rrelu + in-wave LN
// -> bf16 X-tile in per-wave LDS region (row stride 136 shorts to spread banks).
// Phase2: A-frags from LDS, GRU MFMAs gate-by-gate per col-tile.
// Race-free in-place: each wave reads/writes only its own 16 rows (rows%16==0).
template<bool HAS_H>
__global__ void __launch_bounds__(256) k_whlngru(const float* __restrict__ AGG,
    float* H, const short* __restrict__ Bwh, const short* __restrict__ Bih,
    const short* __restrict__ Bhh, const float* __restrict__ lng,
    const float* __restrict__ lnb, const float* __restrict__ bih,
    const float* __restrict__ bhh, int rows){
  __shared__ short xtile[4 * 16 * XPAD];
  short* xl = xtile + (threadIdx.x >> 6) * 16 * XPAD;
  const int lane = threadIdx.x & 63;
  int wave = (int)((blockIdx.x * blockDim.x + threadIdx.x) >> 6);
  if (wave * 16 >= rows) return;
  int r0 = wave * 16;
  if (r0 + 16 > rows) r0 = rows - 16;
  r0 = __builtin_amdgcn_readfirstlane(r0);
  const int arow = lane & 15;
  const int koff = (lane >> 4) << 3;
  const int lrbase = (lane >> 4) << 2;         // local row base for C/D regs

  // ---- phase 1: acc[ct] = (AGG @ Wh) tile, rrelu
  short8 aa[4];
#pragma unroll
  for (int ks = 0; ks < 4; ++ks)
    aa[ks] = ld_frag_f32(AGG + (size_t)(r0 + arow) * DD + ks*32 + koff);
  f32x4 acc[8];
#pragma unroll
  for (int ct = 0; ct < 8; ++ct){
    acc[ct] = (f32x4)0.f;
#pragma unroll
    for (int ks = 0; ks < 4; ++ks){
      short8 bw = *reinterpret_cast<const short8*>(Bwh + ((size_t)(ct*4 + ks)*64 + lane)*8);
      acc[ct] = __builtin_amdgcn_mfma_f32_16x16x32_bf16(aa[ks], bw, acc[ct], 0, 0, 0);
    }
  }
#pragma unroll
  for (int ct = 0; ct < 8; ++ct)
#pragma unroll
    for (int reg = 0; reg < 4; ++reg) acc[ct][reg] = rrelu_f(acc[ct][reg]);

  // ---- in-wave LayerNorm per row (row lives in one 16-lane group)
  float mu[4], rs[4];
#pragma unroll
  for (int reg = 0; reg < 4; ++reg){
    float s = 0.f, ss = 0.f;
#pragma unroll
    for (int ct = 0; ct < 8; ++ct){ float v = acc[ct][reg]; s += v; ss += v*v; }
    s = red16(s); ss = red16(ss);
    float m = s * (1.0f/128.0f);
    float var = ss * (1.0f/128.0f) - m*m;
    mu[reg] = m;
    rs[reg] = rsqrtf(var + LNEPS);
  }
  // normalize + affine, write bf16 X-tile to LDS
#pragma unroll
  for (int ct = 0; ct < 8; ++ct){
    int col = ct*16 + (lane & 15);
    float gv = lng[col], bv = lnb[col];
#pragma unroll
    for (int reg = 0; reg < 4; ++reg){
      float xn = (acc[ct][reg] - mu[reg]) * rs[reg] * gv + bv;
      xl[(lrbase + reg) * XPAD + col] = bf16b(xn);
    }
  }

  // ---- phase 2: GRU. A-frags of X from LDS; H-frags from global.
  short8 ax[4], ah8[4];
#pragma unroll
  for (int ks = 0; ks < 4; ++ks)
    ax[ks] = *reinterpret_cast<const short8*>(&xl[arow * XPAD + ks*32 + koff]);
  if (HAS_H){
#pragma unroll
    for (int ks = 0; ks < 4; ++ks)
      ah8[ks] = ld_frag_f32(H + (size_t)(r0 + arow) * DD + ks*32 + koff);
  }

#pragma unroll
  for (int ct = 0; ct < 8; ++ct){
    f32x4 air = (f32x4)0.f, aiz = (f32x4)0.f, ain = (f32x4)0.f;
    f32x4 ahr = (f32x4)0.f, ahz = (f32x4)0.f, ahn = (f32x4)0.f;
#pragma unroll
    for (int ks = 0; ks < 4; ++ks){
      short8 b0 = *reinterpret_cast<const short8*>(Bih + ((size_t)((0*8 + ct)*4 + ks)*64 + lane)*8);
      short8 b1 = *reinterpret_cast<const short8*>(Bih + ((size_t)((8 + ct)*4 + ks)*64 + lane)*8);
      short8 b2 = *reinterpret_cast<const short8*>(Bih + ((size_t)((16 + ct)*4 + ks)*64 + lane)*8);
      air = __builtin_amdgcn_mfma_f32_16x16x32_bf16(ax[ks], b0, air, 0, 0, 0);
      aiz = __builtin_amdgcn_mfma_f32_16x16x32_bf16(ax[ks], b1, aiz, 0, 0, 0);
      ain = __builtin_amdgcn_mfma_f32_16x16x32_bf16(ax[ks], b2, ain, 0, 0, 0);
      if (HAS_H){
        short8 c0 = *reinterpret_cast<const short8*>(Bhh + ((size_t)((0*8 + ct)*4 + ks)*64 + lane)*8);
        short8 c1 = *reinterpret_cast<const short8*>(Bhh + ((size_t)((8 + ct)*4 + ks)*64 + lane)*8);
        short8 c2 = *reinterpret_cast<const short8*>(Bhh + ((size_t)((16 + ct)*4 + ks)*64 + lane)*8);
        ahr = __builtin_amdgcn_mfma_f32_16x16x32_bf16(ah8[ks], c0, ahr, 0, 0, 0);
        ahz = __builtin_amdgcn_mfma_f32_16x16x32_bf16(ah8[ks], c1, ahz, 0, 0, 0);
        ahn = __builtin_amdgcn_mfma_f32_16x16x32_bf16(ah8[ks], c2, ahn, 0, 0, 0);
      }
    }
    int col = ct*16 + (lane & 15);
    float bi_r = bih[col], bi_z = bih[128 + col], bi_n = bih[256 + col];
    float bh_r = bhh[col], bh_z = bhh[128 + col], bh_n = bhh[256 + col];
#pragma unroll
    for (int reg = 0; reg < 4; ++reg){
      int row = r0 + lrbase + reg;
      float gi_r = air[reg] + bi_r;
      float gi_z = aiz[reg] + bi_z;
      float gi_n = ain[reg] + bi_n;
      float gh_r = (HAS_H ? ahr[reg] : 0.f) + bh_r;
      float gh_z = (HAS_H ? ahz[reg] : 0.f) + bh_z;
      float gh_n = (HAS_H ? ahn[reg] : 0.f) + bh_n;
      float rg = sigm(gi_r + gh_r);
      float zg = sigm(gi_z + gh_z);
      float ng = tanhf(gi_n + rg * gh_n);
      float hp = HAS_H ? H[(size_t)row * DD + col] : 0.f;
      H[(size_t)row * DD + col] = (1.f - zg) * ng + zg * hp;
    }
  }
}

// ---- scores = H @ wf ; record max-index winner per (batch,ent) slot
__global__ void __launch_bounds__(256) k_score(const float* __restrict__ Hf,
    const float* __restrict__ wf, const int* __restrict__ nb, const int* __restrict__ ne,
    float* __restrict__ scores, int* __restrict__ winner, int rows, int NENT){
  const int lane = threadIdx.x & 63;
  int wave = (int)((blockIdx.x * blockDim.x + threadIdx.x) >> 6);
  if (wave >= rows) return;
  int row = __builtin_amdgcn_readfirstlane(wave);
  float v = Hf[(size_t)row*DD + lane] * wf[lane] + Hf[(size_t)row*DD + 64 + lane] * wf[64 + lane];
  float s = wave_sum(v);
  if (lane == 0){
    scores[row] = s;
    int slot = nb[row] * NENT + ne[row];
    atomicMax(&winner[slot], row);
  }
}

__global__ void __launch_bounds__(256) k_scatter(const float* __restrict__ scores,
    const int* __restrict__ winner, const int* __restrict__ nb, const int* __restrict__ ne,
    float* __restrict__ out, int rows, int NENT){
  int n = blockIdx.x * blockDim.x + threadIdx.x;
  if (n < rows){
    int slot = nb[n] * NENT + ne[n];
    if (winner[slot] == n) out[slot] = scores[n];
  }
}

extern "C" void kernel_launch(void* const* d_in, const int* in_sizes, int n_in,
                              void* d_out, int out_size, void* d_ws, size_t ws_size,
                              hipStream_t stream){
  const float* hidden0 = (const float*)d_in[0];
  const float* rel0    = (const float*)d_in[1];
  const int* batch_idx = (const int*)d_in[2];
  const int* rel_i     = (const int*)d_in[3];
  const int* sub       = (const int*)d_in[4];
  const int* obj       = (const int*)d_in[5];
  const int* q_rel     = (const int*)d_in[6];
  const int* nb        = (const int*)d_in[7];
  const int* ne        = (const int*)d_in[8];
  const float* Ws      = (const float*)d_in[9];
  const float* Wr      = (const float*)d_in[10];
  const float* Wqr_w   = (const float*)d_in[11];
  const float* Wqr_b   = (const float*)d_in[12];
  const float* Wal_w   = (const float*)d_in[13];
  const float* Wal_b   = (const float*)d_in[14];
  const float* Wh      = (const float*)d_in[15];
  const float* rt_w    = (const float*)d_in[16];
  const float* rt_b    = (const float*)d_in[17];
  const float* ln_g    = (const float*)d_in[18];
  const float* ln_b    = (const float*)d_in[19];
  const float* lnr_g   = (const float*)d_in[20];
  const float* lnr_b   = (const float*)d_in[21];
  const float* wih     = (const float*)d_in[22];
  const float* whh     = (const float*)d_in[23];
  const float* bih     = (const float*)d_in[24];
  const float* bhh     = (const float*)d_in[25];
  const float* wfin    = (const float*)d_in[26];

  const int N    = in_sizes[0] / DD;
  const int NR   = in_sizes[1] / DD;
  const int E    = in_sizes[2];
  const int Bc   = in_sizes[6];
  const int L    = in_sizes[14];
  const int Rp1  = NR / Bc;
  const int NENT = out_size / Bc;

  char* wsp = (char*)d_ws;
  auto alloc = [&](size_t bytes) -> void* {
    void* p = (void*)wsp;
    wsp += (bytes + 255) & ~(size_t)255;
    return p;
  };
  float* AGG     = (float*)alloc((size_t)N * DD * 4);
  float* HBUF    = (float*)alloc((size_t)N * DD * 4);
  float* rel_cur = (float*)alloc((size_t)NR * DD * 4);
  float* hsW     = (float*)alloc((size_t)N * AA * 4);
  float* hrW     = (float*)alloc((size_t)NR * AA * 4);
  float* qr      = (float*)alloc((size_t)Bc * AA * 4);
  short* Bih     = (short*)alloc((size_t)(GG/16) * 4 * 64 * 8 * 2);
  short* Bhh     = (short*)alloc((size_t)(GG/16) * 4 * 64 * 8 * 2);
  short* Bws     = (short*)alloc((size_t)L * 4 * 4 * 64 * 8 * 2);
  short* Bwr     = (short*)alloc((size_t)L * 4 * 4 * 64 * 8 * 2);
  short* Bwh     = (short*)alloc((size_t)L * 8 * 4 * 64 * 8 * 2);
  float* scores  = (float*)alloc((size_t)N * 4);
  int*   winner  = (int*)alloc((size_t)Bc * NENT * 4);
  int*   deg     = (int*)alloc((size_t)N * 4);
  int*   row_st  = (int*)alloc((size_t)(N + 1) * 4);
  int*   cursor  = (int*)alloc((size_t)N * 4);
  int*   perm    = (int*)alloc((size_t)E * 4);
  int*   bsum    = (int*)alloc((size_t)1024 * 4);
  (void)ws_size; (void)n_in;

  hipMemcpyAsync(rel_cur, rel0, (size_t)NR * DD * 4, hipMemcpyDeviceToDevice, stream);
  {
    int totg = (GG/16) * 4 * 64;
    k_prep_bfrag<<<(totg + 255)/256, 256, 0, stream>>>(wih, Bih, GG);
    k_prep_bfrag<<<(totg + 255)/256, 256, 0, stream>>>(whh, Bhh, GG);
    int tot64 = 4 * 4 * 64;          // C=64 fragments
    int tot128 = 8 * 4 * 64;         // C=128 fragments
    for (int i = 0; i < L; ++i){
      k_prep_bfrag_km<<<(tot64 + 255)/256, 256, 0, stream>>>(Ws + (size_t)i*DD*AA, Bws + (size_t)i*tot64*8, AA, AA);
      k_prep_bfrag_km<<<(tot64 + 255)/256, 256, 0, stream>>>(Wr + (size_t)i*DD*AA, Bwr + (size_t)i*tot64*8, AA, AA);
      k_prep_bfrag_km<<<(tot128 + 255)/256, 256, 0, stream>>>(Wh + (size_t)i*DD*DD, Bwh + (size_t)i*tot128*8, DD, DD);
    }
  }
  hipMemsetAsync(d_out, 0, (size_t)out_size * 4, stream);
  hipMemsetAsync(winner, 0xFF, (size_t)Bc * NENT * 4, stream);

  // ---- build CSR over obj (edges constant across layers)
  hipMemsetAsync(deg, 0, (size_t)N * 4, stream);
  hipMemsetAsync(cursor, 0, (size_t)N * 4, stream);
  k_hist<<<(E + 255)/256, 256, 0, stream>>>(obj, deg, E);
  {
    int nb1 = (N + 1023)/1024;
    k_scan1<<<nb1, 1024, 0, stream>>>(deg, row_st, bsum, N);
    k_scan2<<<1, 1024, 0, stream>>>(bsum, nb1);
    k_scan3<<<(N + 255)/256, 256, 0, stream>>>(row_st, bsum, N, E);
  }
  k_scatter_edges<<<(E + 255)/256, 256, 0, stream>>>(obj, row_st, cursor, perm, E);

  const float* hid_in = hidden0;
  auto blocks4 = [](int waves){ return (waves + 3) / 4; };
  const int tot64 = 4 * 4 * 64;
  const int tot128 = 8 * 4 * 64;

  for (int i = 0; i < L; ++i){
    k_rel_transfer<<<blocks4(NR), 256, 0, stream>>>(rel_cur,
        rt_w + (size_t)i*DD*DD, rt_b + (size_t)i*DD,
        lnr_g + (size_t)i*DD, lnr_b + (size_t)i*DD, NR);
    k_proj_mfma<<<blocks4((N+15)/16), 256, 0, stream>>>(hid_in, Bws + (size_t)i*tot64*8, hsW, N);
    k_proj_mfma<<<blocks4((NR+15)/16), 256, 0, stream>>>(rel_cur, Bwr + (size_t)i*tot64*8, hrW, NR);
    k_projq<<<blocks4(Bc), 256, 0, stream>>>(rel_cur, Wqr_w + (size_t)i*DD*AA,
        Wqr_b + (size_t)i*AA, q_rel, qr, Bc, Rp1);
    k_edge_csr<<<blocks4(N), 256, 0, stream>>>(hid_in, rel_cur, hsW, hrW, qr,
        Wal_w + (size_t)i*AA, Wal_b + i,
        sub, batch_idx, rel_i, row_st, perm, AGG, N, Rp1);
    {
      int waves = (N + 15)/16;
      if (i == 0)
        k_whlngru<false><<<blocks4(waves), 256, 0, stream>>>(AGG, HBUF,
            Bwh + (size_t)i*tot128*8, Bih, Bhh,
            ln_g + (size_t)i*DD, ln_b + (size_t)i*DD, bih, bhh, N);
      else
        k_whlngru<true><<<blocks4(waves), 256, 0, stream>>>(AGG, HBUF,
            Bwh + (size_t)i*tot128*8, Bih, Bhh,
            ln_g + (size_t)i*DD, ln_b + (size_t)i*DD, bih, bhh, N);
    }
    k_ln_rows<<<blocks4(NR), 256, 0, stream>>>(rel_cur,
        lnr_g + (size_t)i*DD, lnr_b + (size_t)i*DD, NR);
    hid_in = HBUF;
  }

  k_score<<<blocks4(N), 256, 0, stream>>>(hid_in, wfin, nb, ne, scores, winner, N, NENT);
  k_scatter<<<(N + 255)/256, 256, 0, stream>>>(scores, winner, nb, ne, (float*)d_out, N, NENT);
}

// Round 6
// 603.587 us; speedup vs baseline: 3.8142x; 1.0877x over previous
//
#include <hip/hip_runtime.h>
#include <hip/hip_bf16.h>

constexpr int DD = 128;   // hidden dim D
constexpr int AA = 64;    // attention dim A
constexpr int GG = 384;   // 3*D (GRU gates)
constexpr int XPAD = 136; // LDS X-tile row stride in shorts (128 + 8 pad)
constexpr int GTS = 192;  // gather-table row stride in shorts: 64 proj + 128 x

#define SLOPE_F 0.22916666666666666f
#define LNEPS   1e-5f

typedef __attribute__((ext_vector_type(8))) short short8;
typedef __attribute__((ext_vector_type(4))) float f32x4;

static __device__ __forceinline__ float wave_sum(float v){
#pragma unroll
  for (int off = 32; off > 0; off >>= 1) v += __shfl_xor(v, off, 64);
  return v;
}
static __device__ __forceinline__ float red16(float v){
#pragma unroll
  for (int off = 1; off < 16; off <<= 1) v += __shfl_xor(v, off, 64);
  return v;
}
static __device__ __forceinline__ float sigm(float x){ return 1.0f / (1.0f + __expf(-x)); }
static __device__ __forceinline__ float rrelu_f(float x){ return x >= 0.0f ? x : SLOPE_F * x; }
static __device__ __forceinline__ short bf16b(float f){
  __hip_bfloat16 h = __float2bfloat16(f);
  return *reinterpret_cast<short*>(&h);
}
static __device__ __forceinline__ float b2f(unsigned short u){
  return __uint_as_float(((unsigned int)u) << 16);
}
static __device__ __forceinline__ float b2f_lo(unsigned int x){
  return __uint_as_float(x << 16);
}
static __device__ __forceinline__ float b2f_hi(unsigned int x){
  return __uint_as_float(x & 0xffff0000u);
}
static __device__ __forceinline__ short8 ld_frag_f32(const float* p){
  float4 f0 = *(const float4*)p;
  float4 f1 = *(const float4*)(p + 4);
  short8 v;
  v[0]=bf16b(f0.x); v[1]=bf16b(f0.y); v[2]=bf16b(f0.z); v[3]=bf16b(f0.w);
  v[4]=bf16b(f1.x); v[5]=bf16b(f1.y); v[6]=bf16b(f1.z); v[7]=bf16b(f1.w);
  return v;
}

// ---- rel = LN(rel + relu(rel @ rtw + rtb)); one row per wave, in place
__global__ void __launch_bounds__(256) k_rel_transfer(float* __restrict__ rel,
    const float* __restrict__ rtw, const float* __restrict__ rtb,
    const float* __restrict__ g, const float* __restrict__ b, int rows){
  const int lane = threadIdx.x & 63;
  int wave = (int)((blockIdx.x * blockDim.x + threadIdx.x) >> 6);
  if (wave >= rows) return;
  int row = __builtin_amdgcn_readfirstlane(wave);
  const float* x = rel + (size_t)row * DD;
  float y0 = 0.f, y1 = 0.f;
#pragma unroll 4
  for (int d = 0; d < DD; ++d){
    float xd = x[d];
    y0 = fmaf(xd, rtw[d*DD + lane],      y0);
    y1 = fmaf(xd, rtw[d*DD + 64 + lane], y1);
  }
  float t0 = x[lane]      + fmaxf(y0 + rtb[lane],      0.f);
  float t1 = x[64 + lane] + fmaxf(y1 + rtb[64 + lane], 0.f);
  float mu = wave_sum(t0 + t1) * (1.0f/128.0f);
  float e0 = t0 - mu, e1 = t1 - mu;
  float var = wave_sum(e0*e0 + e1*e1) * (1.0f/128.0f);
  float rs = rsqrtf(var + LNEPS);
  float* o = rel + (size_t)row * DD;
  o[lane]      = e0 * rs * g[lane]      + b[lane];
  o[64 + lane] = e1 * rs * g[64 + lane] + b[64 + lane];
}

// ---- in-place LayerNorm of rows
__global__ void __launch_bounds__(256) k_ln_rows(float* __restrict__ X,
    const float* __restrict__ g, const float* __restrict__ b, int rows){
  const int lane = threadIdx.x & 63;
  int wave = (int)((blockIdx.x * blockDim.x + threadIdx.x) >> 6);
  if (wave >= rows) return;
  int row = __builtin_amdgcn_readfirstlane(wave);
  float* x = X + (size_t)row * DD;
  float t0 = x[lane], t1 = x[64 + lane];
  float mu = wave_sum(t0 + t1) * (1.0f/128.0f);
  float e0 = t0 - mu, e1 = t1 - mu;
  float var = wave_sum(e0*e0 + e1*e1) * (1.0f/128.0f);
  float rs = rsqrtf(var + LNEPS);
  x[lane]      = e0 * rs * g[lane]      + b[lane];
  x[64 + lane] = e1 * rs * g[64 + lane] + b[64 + lane];
}

// ---- prep bf16 B-fragments from k-major weight W[K=128][C] (ldc = C)
__global__ void __launch_bounds__(256) k_prep_bfrag_km(const float* __restrict__ W,
    short* __restrict__ out, int C, int ldc){
  int idx = blockIdx.x * blockDim.x + threadIdx.x;
  int total = (C >> 4) * 4 * 64;
  if (idx >= total) return;
  int lane = idx & 63, ks = (idx >> 6) & 3, ct = idx >> 8;
  int k = ks*32 + ((lane >> 4) << 3);
  int c = (ct << 4) + (lane & 15);
  short8 v;
#pragma unroll
  for (int j = 0; j < 8; ++j) v[j] = bf16b(W[(size_t)(k + j)*ldc + c]);
  *reinterpret_cast<short8*>(out + (size_t)idx * 8) = v;
}

// ---- prep bf16 B-fragments from c-major weight W[Nc][128] (PyTorch [out,in])
__global__ void __launch_bounds__(256) k_prep_bfrag(const float* __restrict__ W,
    short* __restrict__ out, int Nc){
  int idx = blockIdx.x * blockDim.x + threadIdx.x;
  int total = (Nc >> 4) * 4 * 64;
  if (idx >= total) return;
  int lane = idx & 63, ks = (idx >> 6) & 3, ct = idx >> 8;
  int k = ks*32 + ((lane >> 4) << 3);
  int c = (ct << 4) + (lane & 15);
  const float* src = W + (size_t)c * DD + k;
  short8 v;
#pragma unroll
  for (int j = 0; j < 8; ++j) v[j] = bf16b(src[j]);
  *reinterpret_cast<short8*>(out + (size_t)idx * 8) = v;
}

// ---- MFMA projection + fused bf16 gather-table build.
// GT[row] = [proj(64 bf16) | x(128 bf16)], row stride GTS=192 shorts.
// One wave = 16 rows x 64 cols. X-copy reuses the A-fragments (already bf16).
__global__ void __launch_bounds__(256) k_proj_gt(const float* __restrict__ X,
    const short* __restrict__ Bf, unsigned short* __restrict__ GT, int rows){
  const int lane = threadIdx.x & 63;
  int wave = (int)((blockIdx.x * blockDim.x + threadIdx.x) >> 6);
  int r0 = wave * 16;
  if (r0 >= rows) return;
  if (r0 + 16 > rows) r0 = rows - 16;   // output-only overlap, safe
  r0 = __builtin_amdgcn_readfirstlane(r0);
  const int arow = lane & 15;
  const int koff = (lane >> 4) << 3;
  short8 ax[4];
#pragma unroll
  for (int ks = 0; ks < 4; ++ks){
    ax[ks] = ld_frag_f32(X + (size_t)(r0 + arow) * DD + ks*32 + koff);
    // fused X-copy: write the same bf16 data into GT[.., 64 + ks*32 + koff]
    *reinterpret_cast<short8*>((short*)GT + (size_t)(r0 + arow) * GTS + 64 + ks*32 + koff) = ax[ks];
  }
  f32x4 acc[4];
#pragma unroll
  for (int ct = 0; ct < 4; ++ct){
    acc[ct] = (f32x4)0.f;
#pragma unroll
    for (int ks = 0; ks < 4; ++ks){
      short8 bw = *reinterpret_cast<const short8*>(Bf + ((size_t)(ct*4 + ks)*64 + lane)*8);
      acc[ct] = __builtin_amdgcn_mfma_f32_16x16x32_bf16(ax[ks], bw, acc[ct], 0, 0, 0);
    }
  }
#pragma unroll
  for (int ct = 0; ct < 4; ++ct){
    int col = ct*16 + (lane & 15);
#pragma unroll
    for (int reg = 0; reg < 4; ++reg){
      int row = r0 + ((lane >> 4) << 2) + reg;
      ((short*)GT)[(size_t)row*GTS + col] = bf16b(acc[ct][reg]);
    }
  }
}

// ---- qr[b,:] = rel[q_rel[b]+b*Rp1,:] @ Wqr + bias
__global__ void __launch_bounds__(256) k_projq(const float* __restrict__ rel,
    const float* __restrict__ Wqr, const float* __restrict__ bias,
    const int* __restrict__ q_rel, float* __restrict__ out, int Bc, int Rp1){
  const int lane = threadIdx.x & 63;
  int wave = (int)((blockIdx.x * blockDim.x + threadIdx.x) >> 6);
  if (wave >= Bc) return;
  int b = __builtin_amdgcn_readfirstlane(wave);
  int f = __builtin_amdgcn_readfirstlane(q_rel[b] + b * Rp1);
  const float* x = rel + (size_t)f * DD;
  float a = 0.f;
#pragma unroll 4
  for (int d = 0; d < DD; ++d) a = fmaf(x[d], Wqr[d*AA + lane], a);
  out[(size_t)b*AA + lane] = a + bias[lane];
}

// ================= CSR build (once per call; obj constant across layers) ====
__global__ void __launch_bounds__(256) k_hist(const int* __restrict__ obj, int* __restrict__ deg, int E){
  int idx = blockIdx.x * blockDim.x + threadIdx.x;
  if (idx < E) atomicAdd(&deg[obj[idx]], 1);
}

__global__ void __launch_bounds__(1024) k_scan1(const int* __restrict__ deg,
    int* __restrict__ row_start, int* __restrict__ bsum, int n){
  __shared__ int sm[1024];
  int t = threadIdx.x;
  int i = blockIdx.x * 1024 + t;
  int v = (i < n) ? deg[i] : 0;
  sm[t] = v; __syncthreads();
#pragma unroll
  for (int off = 1; off < 1024; off <<= 1){
    int x = (t >= off) ? sm[t - off] : 0;
    __syncthreads();
    sm[t] += x;
    __syncthreads();
  }
  if (i < n) row_start[i] = sm[t] - v;
  if (t == 1023) bsum[blockIdx.x] = sm[1023];
}

__global__ void __launch_bounds__(1024) k_scan2(int* __restrict__ bsum, int nb){
  __shared__ int sm[1024];
  int t = threadIdx.x;
  int v = (t < nb) ? bsum[t] : 0;
  sm[t] = v; __syncthreads();
#pragma unroll
  for (int off = 1; off < 1024; off <<= 1){
    int x = (t >= off) ? sm[t - off] : 0;
    __syncthreads();
    sm[t] += x;
    __syncthreads();
  }
  if (t < nb) bsum[t] = sm[t] - v;
}

__global__ void __launch_bounds__(256) k_scan3(int* __restrict__ row_start,
    const int* __restrict__ bsum, int n, int E){
  int i = blockIdx.x * blockDim.x + threadIdx.x;
  if (i < n) row_start[i] += bsum[i >> 10];
  if (i == 0) row_start[n] = E;
}

__global__ void __launch_bounds__(256) k_scatter_edges(const int* __restrict__ obj,
    const int* __restrict__ row_start, int* __restrict__ cursor,
    int* __restrict__ perm, int E){
  int e = blockIdx.x * blockDim.x + threadIdx.x;
  if (e < E){
    int o = obj[e];
    int pos = row_start[o] + atomicAdd(&cursor[o], 1);
    perm[pos] = e;
  }
}

// ---- CSR edge kernel over bf16 fused tables. One wave per node.
// pre phase: lane = dim (bf16 gathers); msg phase: lane = dims {2l,2l+1} via u32.
// agg written once per node as coalesced float2.
__global__ void __launch_bounds__(256) k_edge_csr(
    const unsigned short* __restrict__ GT, const unsigned short* __restrict__ RT,
    const float* __restrict__ qr,
    const float* __restrict__ wal, const float* __restrict__ walb_p,
    const int* __restrict__ sub, const int* __restrict__ bidx,
    const int* __restrict__ reli, const int* __restrict__ row_start,
    const int* __restrict__ perm, float* __restrict__ agg, int Nn, int Rp1){
  const int lane = threadIdx.x & 63;
  int wave = (int)((blockIdx.x * blockDim.x + threadIdx.x) >> 6);
  if (wave >= Nn) return;
  int o = __builtin_amdgcn_readfirstlane(wave);
  const int s0 = __builtin_amdgcn_readfirstlane(row_start[o]);
  const int s1 = __builtin_amdgcn_readfirstlane(row_start[o + 1]);
  const float wa = wal[lane];
  const float wb = walb_p[0];
  float acc0 = 0.f, acc1 = 0.f;
  for (int base = s0; base < s1; base += 64){
    int cnt = s1 - base; if (cnt > 64) cnt = 64;
    int jj = base + lane;
    int ev = (jj < s1) ? perm[jj] : 0;
    int sv = sub[ev];
    int bv = bidx[ev];
    int fv = reli[ev] + bv * Rp1;
    for (int k = 0; k < cnt; ++k){
      int s  = __shfl(sv, k);
      int f  = __shfl(fv, k);
      int bb = __shfl(bv, k);
      const unsigned short* gs = GT + (size_t)s * GTS;
      const unsigned short* rf = RT + (size_t)f * GTS;
      float pre = b2f(gs[lane]) + b2f(rf[lane]) + qr[(size_t)bb*AA + lane];
      float t = rrelu_f(pre);
      float al = sigm(wave_sum(t * wa) + wb);
      unsigned int hsp = *reinterpret_cast<const unsigned int*>(gs + 64 + 2*lane);
      unsigned int hrp = *reinterpret_cast<const unsigned int*>(rf + 64 + 2*lane);
      acc0 = fmaf(al, b2f_lo(hsp) + b2f_lo(hrp), acc0);
      acc1 = fmaf(al, b2f_hi(hsp) + b2f_hi(hrp), acc1);
    }
  }
  float2 outv; outv.x = acc0; outv.y = acc1;
  *reinterpret_cast<float2*>(agg + (size_t)o*DD + 2*lane) = outv;
}

// ---- FUSED: H = gru(x = LN(rrelu(AGG@Wh)), h = H), in place.
template<bool HAS_H>
__global__ void __launch_bounds__(256) k_whlngru(const float* __restrict__ AGG,
    float* H, const short* __restrict__ Bwh, const short* __restrict__ Bih,
    const short* __restrict__ Bhh, const float* __restrict__ lng,
    const float* __restrict__ lnb, const float* __restrict__ bih,
    const float* __restrict__ bhh, int rows){
  __shared__ short xtile[4 * 16 * XPAD];
  short* xl = xtile + (threadIdx.x >> 6) * 16 * XPAD;
  const int lane = threadIdx.x & 63;
  int wave = (int)((blockIdx.x * blockDim.x + threadIdx.x) >> 6);
  if (wave * 16 >= rows) return;
  int r0 = wave * 16;
  if (r0 + 16 > rows) r0 = rows - 16;
  r0 = __builtin_amdgcn_readfirstlane(r0);
  const int arow = lane & 15;
  const int koff = (lane >> 4) << 3;
  const int lrbase = (lane >> 4) << 2;

  // ---- phase 1: acc[ct] = (AGG @ Wh) tile, rrelu
  short8 aa[4];
#pragma unroll
  for (int ks = 0; ks < 4; ++ks)
    aa[ks] = ld_frag_f32(AGG + (size_t)(r0 + arow) * DD + ks*32 + koff);
  f32x4 acc[8];
#pragma unroll
  for (int ct = 0; ct < 8; ++ct){
    acc[ct] = (f32x4)0.f;
#pragma unroll
    for (int ks = 0; ks < 4; ++ks){
      short8 bw = *reinterpret_cast<const short8*>(Bwh + ((size_t)(ct*4 + ks)*64 + lane)*8);
      acc[ct] = __builtin_amdgcn_mfma_f32_16x16x32_bf16(aa[ks], bw, acc[ct], 0, 0, 0);
    }
  }
#pragma unroll
  for (int ct = 0; ct < 8; ++ct)
#pragma unroll
    for (int reg = 0; reg < 4; ++reg) acc[ct][reg] = rrelu_f(acc[ct][reg]);

  // ---- in-wave LayerNorm per row
  float mu[4], rs[4];
#pragma unroll
  for (int reg = 0; reg < 4; ++reg){
    float s = 0.f, ss = 0.f;
#pragma unroll
    for (int ct = 0; ct < 8; ++ct){ float v = acc[ct][reg]; s += v; ss += v*v; }
    s = red16(s); ss = red16(ss);
    float m = s * (1.0f/128.0f);
    float var = ss * (1.0f/128.0f) - m*m;
    mu[reg] = m;
    rs[reg] = rsqrtf(var + LNEPS);
  }
#pragma unroll
  for (int ct = 0; ct < 8; ++ct){
    int col = ct*16 + (lane & 15);
    float gv = lng[col], bv = lnb[col];
#pragma unroll
    for (int reg = 0; reg < 4; ++reg){
      float xn = (acc[ct][reg] - mu[reg]) * rs[reg] * gv + bv;
      xl[(lrbase + reg) * XPAD + col] = bf16b(xn);
    }
  }

  // ---- phase 2: GRU
  short8 ax[4], ah8[4];
#pragma unroll
  for (int ks = 0; ks < 4; ++ks)
    ax[ks] = *reinterpret_cast<const short8*>(&xl[arow * XPAD + ks*32 + koff]);
  if (HAS_H){
#pragma unroll
    for (int ks = 0; ks < 4; ++ks)
      ah8[ks] = ld_frag_f32(H + (size_t)(r0 + arow) * DD + ks*32 + koff);
  }

#pragma unroll
  for (int ct = 0; ct < 8; ++ct){
    f32x4 air = (f32x4)0.f, aiz = (f32x4)0.f, ain = (f32x4)0.f;
    f32x4 ahr = (f32x4)0.f, ahz = (f32x4)0.f, ahn = (f32x4)0.f;
#pragma unroll
    for (int ks = 0; ks < 4; ++ks){
      short8 b0 = *reinterpret_cast<const short8*>(Bih + ((size_t)((0*8 + ct)*4 + ks)*64 + lane)*8);
      short8 b1 = *reinterpret_cast<const short8*>(Bih + ((size_t)((8 + ct)*4 + ks)*64 + lane)*8);
      short8 b2 = *reinterpret_cast<const short8*>(Bih + ((size_t)((16 + ct)*4 + ks)*64 + lane)*8);
      air = __builtin_amdgcn_mfma_f32_16x16x32_bf16(ax[ks], b0, air, 0, 0, 0);
      aiz = __builtin_amdgcn_mfma_f32_16x16x32_bf16(ax[ks], b1, aiz, 0, 0, 0);
      ain = __builtin_amdgcn_mfma_f32_16x16x32_bf16(ax[ks], b2, ain, 0, 0, 0);
      if (HAS_H){
        short8 c0 = *reinterpret_cast<const short8*>(Bhh + ((size_t)((0*8 + ct)*4 + ks)*64 + lane)*8);
        short8 c1 = *reinterpret_cast<const short8*>(Bhh + ((size_t)((8 + ct)*4 + ks)*64 + lane)*8);
        short8 c2 = *reinterpret_cast<const short8*>(Bhh + ((size_t)((16 + ct)*4 + ks)*64 + lane)*8);
        ahr = __builtin_amdgcn_mfma_f32_16x16x32_bf16(ah8[ks], c0, ahr, 0, 0, 0);
        ahz = __builtin_amdgcn_mfma_f32_16x16x32_bf16(ah8[ks], c1, ahz, 0, 0, 0);
        ahn = __builtin_amdgcn_mfma_f32_16x16x32_bf16(ah8[ks], c2, ahn, 0, 0, 0);
      }
    }
    int col = ct*16 + (lane & 15);
    float bi_r = bih[col], bi_z = bih[128 + col], bi_n = bih[256 + col];
    float bh_r = bhh[col], bh_z = bhh[128 + col], bh_n = bhh[256 + col];
#pragma unroll
    for (int reg = 0; reg < 4; ++reg){
      int row = r0 + lrbase + reg;
      float gi_r = air[reg] + bi_r;
      float gi_z = aiz[reg] + bi_z;
      float gi_n = ain[reg] + bi_n;
      float gh_r = (HAS_H ? ahr[reg] : 0.f) + bh_r;
      float gh_z = (HAS_H ? ahz[reg] : 0.f) + bh_z;
      float gh_n = (HAS_H ? ahn[reg] : 0.f) + bh_n;
      float rg = sigm(gi_r + gh_r);
      float zg = sigm(gi_z + gh_z);
      float ng = tanhf(gi_n + rg * gh_n);
      float hp = HAS_H ? H[(size_t)row * DD + col] : 0.f;
      H[(size_t)row * DD + col] = (1.f - zg) * ng + zg * hp;
    }
  }
}

// ---- scores = H @ wf ; record max-index winner per (batch,ent) slot
__global__ void __launch_bounds__(256) k_score(const float* __restrict__ Hf,
    const float* __restrict__ wf, const int* __restrict__ nb, const int* __restrict__ ne,
    float* __restrict__ scores, int* __restrict__ winner, int rows, int NENT){
  const int lane = threadIdx.x & 63;
  int wave = (int)((blockIdx.x * blockDim.x + threadIdx.x) >> 6);
  if (wave >= rows) return;
  int row = __builtin_amdgcn_readfirstlane(wave);
  float v = Hf[(size_t)row*DD + lane] * wf[lane] + Hf[(size_t)row*DD + 64 + lane] * wf[64 + lane];
  float s = wave_sum(v);
  if (lane == 0){
    scores[row] = s;
    int slot = nb[row] * NENT + ne[row];
    atomicMax(&winner[slot], row);
  }
}

__global__ void __launch_bounds__(256) k_scatter(const float* __restrict__ scores,
    const int* __restrict__ winner, const int* __restrict__ nb, const int* __restrict__ ne,
    float* __restrict__ out, int rows, int NENT){
  int n = blockIdx.x * blockDim.x + threadIdx.x;
  if (n < rows){
    int slot = nb[n] * NENT + ne[n];
    if (winner[slot] == n) out[slot] = scores[n];
  }
}

extern "C" void kernel_launch(void* const* d_in, const int* in_sizes, int n_in,
                              void* d_out, int out_size, void* d_ws, size_t ws_size,
                              hipStream_t stream){
  const float* hidden0 = (const float*)d_in[0];
  const float* rel0    = (const float*)d_in[1];
  const int* batch_idx = (const int*)d_in[2];
  const int* rel_i     = (const int*)d_in[3];
  const int* sub       = (const int*)d_in[4];
  const int* obj       = (const int*)d_in[5];
  const int* q_rel     = (const int*)d_in[6];
  const int* nb        = (const int*)d_in[7];
  const int* ne        = (const int*)d_in[8];
  const float* Ws      = (const float*)d_in[9];
  const float* Wr      = (const float*)d_in[10];
  const float* Wqr_w   = (const float*)d_in[11];
  const float* Wqr_b   = (const float*)d_in[12];
  const float* Wal_w   = (const float*)d_in[13];
  const float* Wal_b   = (const float*)d_in[14];
  const float* Wh      = (const float*)d_in[15];
  const float* rt_w    = (const float*)d_in[16];
  const float* rt_b    = (const float*)d_in[17];
  const float* ln_g    = (const float*)d_in[18];
  const float* ln_b    = (const float*)d_in[19];
  const float* lnr_g   = (const float*)d_in[20];
  const float* lnr_b   = (const float*)d_in[21];
  const float* wih     = (const float*)d_in[22];
  const float* whh     = (const float*)d_in[23];
  const float* bih     = (const float*)d_in[24];
  const float* bhh     = (const float*)d_in[25];
  const float* wfin    = (const float*)d_in[26];

  const int N    = in_sizes[0] / DD;
  const int NR   = in_sizes[1] / DD;
  const int E    = in_sizes[2];
  const int Bc   = in_sizes[6];
  const int L    = in_sizes[14];
  const int Rp1  = NR / Bc;
  const int NENT = out_size / Bc;

  char* wsp = (char*)d_ws;
  auto alloc = [&](size_t bytes) -> void* {
    void* p = (void*)wsp;
    wsp += (bytes + 255) & ~(size_t)255;
    return p;
  };
  float* AGG     = (float*)alloc((size_t)N * DD * 4);
  float* HBUF    = (float*)alloc((size_t)N * DD * 4);
  float* rel_cur = (float*)alloc((size_t)NR * DD * 4);
  unsigned short* GT = (unsigned short*)alloc((size_t)N * GTS * 2);
  unsigned short* RT = (unsigned short*)alloc((size_t)NR * GTS * 2);
  float* qr      = (float*)alloc((size_t)Bc * AA * 4);
  short* Bih     = (short*)alloc((size_t)(GG/16) * 4 * 64 * 8 * 2);
  short* Bhh     = (short*)alloc((size_t)(GG/16) * 4 * 64 * 8 * 2);
  short* Bws     = (short*)alloc((size_t)L * 4 * 4 * 64 * 8 * 2);
  short* Bwr     = (short*)alloc((size_t)L * 4 * 4 * 64 * 8 * 2);
  short* Bwh     = (short*)alloc((size_t)L * 8 * 4 * 64 * 8 * 2);
  float* scores  = (float*)alloc((size_t)N * 4);
  int*   winner  = (int*)alloc((size_t)Bc * NENT * 4);
  int*   deg     = (int*)alloc((size_t)N * 4);
  int*   row_st  = (int*)alloc((size_t)(N + 1) * 4);
  int*   cursor  = (int*)alloc((size_t)N * 4);
  int*   perm    = (int*)alloc((size_t)E * 4);
  int*   bsum    = (int*)alloc((size_t)1024 * 4);
  (void)ws_size; (void)n_in;

  hipMemcpyAsync(rel_cur, rel0, (size_t)NR * DD * 4, hipMemcpyDeviceToDevice, stream);
  {
    int totg = (GG/16) * 4 * 64;
    k_prep_bfrag<<<(totg + 255)/256, 256, 0, stream>>>(wih, Bih, GG);
    k_prep_bfrag<<<(totg + 255)/256, 256, 0, stream>>>(whh, Bhh, GG);
    int tot64 = 4 * 4 * 64;          // C=64 fragments
    int tot128 = 8 * 4 * 64;         // C=128 fragments
    for (int i = 0; i < L; ++i){
      k_prep_bfrag_km<<<(tot64 + 255)/256, 256, 0, stream>>>(Ws + (size_t)i*DD*AA, Bws + (size_t)i*tot64*8, AA, AA);
      k_prep_bfrag_km<<<(tot64 + 255)/256, 256, 0, stream>>>(Wr + (size_t)i*DD*AA, Bwr + (size_t)i*tot64*8, AA, AA);
      k_prep_bfrag_km<<<(tot128 + 255)/256, 256, 0, stream>>>(Wh + (size_t)i*DD*DD, Bwh + (size_t)i*tot128*8, DD, DD);
    }
  }
  hipMemsetAsync(d_out, 0, (size_t)out_size * 4, stream);
  hipMemsetAsync(winner, 0xFF, (size_t)Bc * NENT * 4, stream);

  // ---- build CSR over obj (edges constant across layers)
  hipMemsetAsync(deg, 0, (size_t)N * 4, stream);
  hipMemsetAsync(cursor, 0, (size_t)N * 4, stream);
  k_hist<<<(E + 255)/256, 256, 0, stream>>>(obj, deg, E);
  {
    int nb1 = (N + 1023)/1024;
    k_scan1<<<nb1, 1024, 0, stream>>>(deg, row_st, bsum, N);
    k_scan2<<<1, 1024, 0, stream>>>(bsum, nb1);
    k_scan3<<<(N + 255)/256, 256, 0, stream>>>(row_st, bsum, N, E);
  }
  k_scatter_edges<<<(E + 255)/256, 256, 0, stream>>>(obj, row_st, cursor, perm, E);

  const float* hid_in = hidden0;
  auto blocks4 = [](int waves){ return (waves + 3) / 4; };
  const int tot64 = 4 * 4 * 64;
  const int tot128 = 8 * 4 * 64;

  for (int i = 0; i < L; ++i){
    k_rel_transfer<<<blocks4(NR), 256, 0, stream>>>(rel_cur,
        rt_w + (size_t)i*DD*DD, rt_b + (size_t)i*DD,
        lnr_g + (size_t)i*DD, lnr_b + (size_t)i*DD, NR);
    k_proj_gt<<<blocks4((N+15)/16), 256, 0, stream>>>(hid_in, Bws + (size_t)i*tot64*8, GT, N);
    k_proj_gt<<<blocks4((NR+15)/16), 256, 0, stream>>>(rel_cur, Bwr + (size_t)i*tot64*8, RT, NR);
    k_projq<<<blocks4(Bc), 256, 0, stream>>>(rel_cur, Wqr_w + (size_t)i*DD*AA,
        Wqr_b + (size_t)i*AA, q_rel, qr, Bc, Rp1);
    k_edge_csr<<<blocks4(N), 256, 0, stream>>>(GT, RT, qr,
        Wal_w + (size_t)i*AA, Wal_b + i,
        sub, batch_idx, rel_i, row_st, perm, AGG, N, Rp1);
    {
      int waves = (N + 15)/16;
      if (i == 0)
        k_whlngru<false><<<blocks4(waves), 256, 0, stream>>>(AGG, HBUF,
            Bwh + (size_t)i*tot128*8, Bih, Bhh,
            ln_g + (size_t)i*DD, ln_b + (size_t)i*DD, bih, bhh, N);
      else
        k_whlngru<true><<<blocks4(waves), 256, 0, stream>>>(AGG, HBUF,
            Bwh + (size_t)i*tot128*8, Bih, Bhh,
            ln_g + (size_t)i*DD, ln_b + (size_t)i*DD, bih, bhh, N);
    }
    k_ln_rows<<<blocks4(NR), 256, 0, stream>>>(rel_cur,
        lnr_g + (size_t)i*DD, lnr_b + (size_t)i*DD, NR);
    hid_in = HBUF;
  }

  k_score<<<blocks4(N), 256, 0, stream>>>(hid_in, wfin, nb, ne, scores, winner, N, NENT);
  k_scatter<<<(N + 255)/256, 256, 0, stream>>>(scores, winner, nb, ne, (float*)d_out, N, NENT);
}

// Round 7
// 585.737 us; speedup vs baseline: 3.9304x; 1.0305x over previous
//
#include <hip/hip_runtime.h>
#include <hip/hip_bf16.h>

constexpr int DD = 128;   // hidden dim D
constexpr int AA = 64;    // attention dim A
constexpr int GG = 384;   // 3*D (GRU gates)
constexpr int XPAD = 136; // LDS X-tile row stride in shorts (128 + 8 pad)
constexpr int GTS = 192;  // gather-table row stride in shorts: 64 proj + 128 x

#define SLOPE_F 0.22916666666666666f
#define LNEPS   1e-5f

typedef __attribute__((ext_vector_type(8))) short short8;
typedef __attribute__((ext_vector_type(4))) float f32x4;

static __device__ __forceinline__ float wave_sum(float v){
#pragma unroll
  for (int off = 32; off > 0; off >>= 1) v += __shfl_xor(v, off, 64);
  return v;
}
static __device__ __forceinline__ float red16(float v){
#pragma unroll
  for (int off = 1; off < 16; off <<= 1) v += __shfl_xor(v, off, 64);
  return v;
}
static __device__ __forceinline__ float sigm(float x){ return 1.0f / (1.0f + __expf(-x)); }
static __device__ __forceinline__ float rrelu_f(float x){ return x >= 0.0f ? x : SLOPE_F * x; }
static __device__ __forceinline__ short bf16b(float f){
  __hip_bfloat16 h = __float2bfloat16(f);
  return *reinterpret_cast<short*>(&h);
}
static __device__ __forceinline__ float b2f(unsigned short u){
  return __uint_as_float(((unsigned int)u) << 16);
}
static __device__ __forceinline__ float b2f_lo(unsigned int x){
  return __uint_as_float(x << 16);
}
static __device__ __forceinline__ float b2f_hi(unsigned int x){
  return __uint_as_float(x & 0xffff0000u);
}
static __device__ __forceinline__ short8 ld_frag_f32(const float* p){
  float4 f0 = *(const float4*)p;
  float4 f1 = *(const float4*)(p + 4);
  short8 v;
  v[0]=bf16b(f0.x); v[1]=bf16b(f0.y); v[2]=bf16b(f0.z); v[3]=bf16b(f0.w);
  v[4]=bf16b(f1.x); v[5]=bf16b(f1.y); v[6]=bf16b(f1.z); v[7]=bf16b(f1.w);
  return v;
}

// ---- rel = LN(rel + relu(rel @ rtw + rtb)); one row per wave, in place
__global__ void __launch_bounds__(256) k_rel_transfer(float* __restrict__ rel,
    const float* __restrict__ rtw, const float* __restrict__ rtb,
    const float* __restrict__ g, const float* __restrict__ b, int rows){
  const int lane = threadIdx.x & 63;
  int wave = (int)((blockIdx.x * blockDim.x + threadIdx.x) >> 6);
  if (wave >= rows) return;
  int row = __builtin_amdgcn_readfirstlane(wave);
  const float* x = rel + (size_t)row * DD;
  float y0 = 0.f, y1 = 0.f;
#pragma unroll 4
  for (int d = 0; d < DD; ++d){
    float xd = x[d];
    y0 = fmaf(xd, rtw[d*DD + lane],      y0);
    y1 = fmaf(xd, rtw[d*DD + 64 + lane], y1);
  }
  float t0 = x[lane]      + fmaxf(y0 + rtb[lane],      0.f);
  float t1 = x[64 + lane] + fmaxf(y1 + rtb[64 + lane], 0.f);
  float mu = wave_sum(t0 + t1) * (1.0f/128.0f);
  float e0 = t0 - mu, e1 = t1 - mu;
  float var = wave_sum(e0*e0 + e1*e1) * (1.0f/128.0f);
  float rs = rsqrtf(var + LNEPS);
  float* o = rel + (size_t)row * DD;
  o[lane]      = e0 * rs * g[lane]      + b[lane];
  o[64 + lane] = e1 * rs * g[64 + lane] + b[64 + lane];
}

// ---- in-place LayerNorm of rows
__global__ void __launch_bounds__(256) k_ln_rows(float* __restrict__ X,
    const float* __restrict__ g, const float* __restrict__ b, int rows){
  const int lane = threadIdx.x & 63;
  int wave = (int)((blockIdx.x * blockDim.x + threadIdx.x) >> 6);
  if (wave >= rows) return;
  int row = __builtin_amdgcn_readfirstlane(wave);
  float* x = X + (size_t)row * DD;
  float t0 = x[lane], t1 = x[64 + lane];
  float mu = wave_sum(t0 + t1) * (1.0f/128.0f);
  float e0 = t0 - mu, e1 = t1 - mu;
  float var = wave_sum(e0*e0 + e1*e1) * (1.0f/128.0f);
  float rs = rsqrtf(var + LNEPS);
  x[lane]      = e0 * rs * g[lane]      + b[lane];
  x[64 + lane] = e1 * rs * g[64 + lane] + b[64 + lane];
}

// ---- prep bf16 B-fragments from k-major weight W[K=128][C] (ldc = C)
__global__ void __launch_bounds__(256) k_prep_bfrag_km(const float* __restrict__ W,
    short* __restrict__ out, int C, int ldc){
  int idx = blockIdx.x * blockDim.x + threadIdx.x;
  int total = (C >> 4) * 4 * 64;
  if (idx >= total) return;
  int lane = idx & 63, ks = (idx >> 6) & 3, ct = idx >> 8;
  int k = ks*32 + ((lane >> 4) << 3);
  int c = (ct << 4) + (lane & 15);
  short8 v;
#pragma unroll
  for (int j = 0; j < 8; ++j) v[j] = bf16b(W[(size_t)(k + j)*ldc + c]);
  *reinterpret_cast<short8*>(out + (size_t)idx * 8) = v;
}

// ---- prep bf16 B-fragments from c-major weight W[Nc][128] (PyTorch [out,in])
__global__ void __launch_bounds__(256) k_prep_bfrag(const float* __restrict__ W,
    short* __restrict__ out, int Nc){
  int idx = blockIdx.x * blockDim.x + threadIdx.x;
  int total = (Nc >> 4) * 4 * 64;
  if (idx >= total) return;
  int lane = idx & 63, ks = (idx >> 6) & 3, ct = idx >> 8;
  int k = ks*32 + ((lane >> 4) << 3);
  int c = (ct << 4) + (lane & 15);
  const float* src = W + (size_t)c * DD + k;
  short8 v;
#pragma unroll
  for (int j = 0; j < 8; ++j) v[j] = bf16b(src[j]);
  *reinterpret_cast<short8*>(out + (size_t)idx * 8) = v;
}

// ---- MFMA projection + fused bf16 gather-table build.
// GT[row] = [proj(64 bf16) | x(128 bf16)], row stride GTS=192 shorts.
__global__ void __launch_bounds__(256) k_proj_gt(const float* __restrict__ X,
    const short* __restrict__ Bf, unsigned short* __restrict__ GT, int rows){
  const int lane = threadIdx.x & 63;
  int wave = (int)((blockIdx.x * blockDim.x + threadIdx.x) >> 6);
  int r0 = wave * 16;
  if (r0 >= rows) return;
  if (r0 + 16 > rows) r0 = rows - 16;   // output-only overlap, safe
  r0 = __builtin_amdgcn_readfirstlane(r0);
  const int arow = lane & 15;
  const int koff = (lane >> 4) << 3;
  short8 ax[4];
#pragma unroll
  for (int ks = 0; ks < 4; ++ks){
    ax[ks] = ld_frag_f32(X + (size_t)(r0 + arow) * DD + ks*32 + koff);
    *reinterpret_cast<short8*>((short*)GT + (size_t)(r0 + arow) * GTS + 64 + ks*32 + koff) = ax[ks];
  }
  f32x4 acc[4];
#pragma unroll
  for (int ct = 0; ct < 4; ++ct){
    acc[ct] = (f32x4)0.f;
#pragma unroll
    for (int ks = 0; ks < 4; ++ks){
      short8 bw = *reinterpret_cast<const short8*>(Bf + ((size_t)(ct*4 + ks)*64 + lane)*8);
      acc[ct] = __builtin_amdgcn_mfma_f32_16x16x32_bf16(ax[ks], bw, acc[ct], 0, 0, 0);
    }
  }
#pragma unroll
  for (int ct = 0; ct < 4; ++ct){
    int col = ct*16 + (lane & 15);
#pragma unroll
    for (int reg = 0; reg < 4; ++reg){
      int row = r0 + ((lane >> 4) << 2) + reg;
      ((short*)GT)[(size_t)row*GTS + col] = bf16b(acc[ct][reg]);
    }
  }
}

// ---- qr[b,:] = rel[q_rel[b]+b*Rp1,:] @ Wqr + bias
__global__ void __launch_bounds__(256) k_projq(const float* __restrict__ rel,
    const float* __restrict__ Wqr, const float* __restrict__ bias,
    const int* __restrict__ q_rel, float* __restrict__ out, int Bc, int Rp1){
  const int lane = threadIdx.x & 63;
  int wave = (int)((blockIdx.x * blockDim.x + threadIdx.x) >> 6);
  if (wave >= Bc) return;
  int b = __builtin_amdgcn_readfirstlane(wave);
  int f = __builtin_amdgcn_readfirstlane(q_rel[b] + b * Rp1);
  const float* x = rel + (size_t)f * DD;
  float a = 0.f;
#pragma unroll 4
  for (int d = 0; d < DD; ++d) a = fmaf(x[d], Wqr[d*AA + lane], a);
  out[(size_t)b*AA + lane] = a + bias[lane];
}

// ================= CSR build (once per call; obj constant across layers) ====
__global__ void __launch_bounds__(256) k_hist(const int* __restrict__ obj, int* __restrict__ deg, int E){
  int idx = blockIdx.x * blockDim.x + threadIdx.x;
  if (idx < E) atomicAdd(&deg[obj[idx]], 1);
}

__global__ void __launch_bounds__(1024) k_scan1(const int* __restrict__ deg,
    int* __restrict__ row_start, int* __restrict__ bsum, int n){
  __shared__ int sm[1024];
  int t = threadIdx.x;
  int i = blockIdx.x * 1024 + t;
  int v = (i < n) ? deg[i] : 0;
  sm[t] = v; __syncthreads();
#pragma unroll
  for (int off = 1; off < 1024; off <<= 1){
    int x = (t >= off) ? sm[t - off] : 0;
    __syncthreads();
    sm[t] += x;
    __syncthreads();
  }
  if (i < n) row_start[i] = sm[t] - v;
  if (t == 1023) bsum[blockIdx.x] = sm[1023];
}

__global__ void __launch_bounds__(1024) k_scan2(int* __restrict__ bsum, int nb){
  __shared__ int sm[1024];
  int t = threadIdx.x;
  int v = (t < nb) ? bsum[t] : 0;
  sm[t] = v; __syncthreads();
#pragma unroll
  for (int off = 1; off < 1024; off <<= 1){
    int x = (t >= off) ? sm[t - off] : 0;
    __syncthreads();
    sm[t] += x;
    __syncthreads();
  }
  if (t < nb) bsum[t] = sm[t] - v;
}

__global__ void __launch_bounds__(256) k_scan3(int* __restrict__ row_start,
    const int* __restrict__ bsum, int n, int E){
  int i = blockIdx.x * blockDim.x + threadIdx.x;
  if (i < n) row_start[i] += bsum[i >> 10];
  if (i == 0) row_start[n] = E;
}

__global__ void __launch_bounds__(256) k_scatter_edges(const int* __restrict__ obj,
    const int* __restrict__ row_start, int* __restrict__ cursor,
    int* __restrict__ perm, int E){
  int e = blockIdx.x * blockDim.x + threadIdx.x;
  if (e < E){
    int o = obj[e];
    int pos = row_start[o] + atomicAdd(&cursor[o], 1);
    perm[pos] = e;
  }
}

// ---- CSR edge kernel, 4 edges per wave iteration.
// Wave = 1 node. 4 sub-groups of 16 lanes; group g handles edge k*4+g.
// alpha: 4 dims/lane (8B bf16 loads), 16-lane butterfly reduce.
// msg: 8 dims/lane (16B bf16 loads) -> acc[8]; cross-group reduce at end;
// group 0 stores the 512B row once. No atomics.
__global__ void __launch_bounds__(256) k_edge_csr4(
    const unsigned short* __restrict__ GT, const unsigned short* __restrict__ RT,
    const float* __restrict__ qr,
    const float* __restrict__ wal, const float* __restrict__ walb_p,
    const int* __restrict__ sub, const int* __restrict__ bidx,
    const int* __restrict__ reli, const int* __restrict__ row_start,
    const int* __restrict__ perm, float* __restrict__ agg, int Nn, int Rp1){
  const int lane = threadIdx.x & 63;
  const int g = lane >> 4;
  const int t = lane & 15;
  int wave = (int)((blockIdx.x * blockDim.x + threadIdx.x) >> 6);
  if (wave >= Nn) return;
  int o = __builtin_amdgcn_readfirstlane(wave);
  const int s0 = __builtin_amdgcn_readfirstlane(row_start[o]);
  const int s1 = __builtin_amdgcn_readfirstlane(row_start[o + 1]);
  const float4 wa4 = *reinterpret_cast<const float4*>(wal + t*4);
  const float wb = walb_p[0];
  float acc[8];
#pragma unroll
  for (int i = 0; i < 8; ++i) acc[i] = 0.f;
  for (int base = s0; base < s1; base += 64){
    int cnt = s1 - base; if (cnt > 64) cnt = 64;
    int jj = base + lane;
    int ev = (jj < s1) ? perm[jj] : 0;
    int sv = sub[ev];
    int bv = bidx[ev];
    int fv = reli[ev] + bv * Rp1;
    int iters = (cnt + 3) >> 2;
    for (int k = 0; k < iters; ++k){
      int idx = k*4 + g;
      int s  = __shfl(sv, idx);
      int f  = __shfl(fv, idx);
      int bb = __shfl(bv, idx);
      const unsigned short* gs = GT + (size_t)s * GTS;
      const unsigned short* rf = RT + (size_t)f * GTS;
      // alpha phase: dims t*4 .. t*4+3
      uint2 pg = *reinterpret_cast<const uint2*>(gs + t*4);
      uint2 pr = *reinterpret_cast<const uint2*>(rf + t*4);
      float4 q4 = *reinterpret_cast<const float4*>(qr + (size_t)bb*AA + t*4);
      float p0 = b2f_lo(pg.x) + b2f_lo(pr.x) + q4.x;
      float p1 = b2f_hi(pg.x) + b2f_hi(pr.x) + q4.y;
      float p2 = b2f_lo(pg.y) + b2f_lo(pr.y) + q4.z;
      float p3 = b2f_hi(pg.y) + b2f_hi(pr.y) + q4.w;
      float dotp = rrelu_f(p0)*wa4.x + rrelu_f(p1)*wa4.y
                 + rrelu_f(p2)*wa4.z + rrelu_f(p3)*wa4.w;
#pragma unroll
      for (int off = 1; off < 16; off <<= 1) dotp += __shfl_xor(dotp, off, 64);
      float al = sigm(dotp + wb);
      if (idx >= cnt) al = 0.f;
      // msg phase: dims t*8 .. t*8+7
      uint4 xg = *reinterpret_cast<const uint4*>(gs + 64 + t*8);
      uint4 xr = *reinterpret_cast<const uint4*>(rf + 64 + t*8);
      acc[0] = fmaf(al, b2f_lo(xg.x) + b2f_lo(xr.x), acc[0]);
      acc[1] = fmaf(al, b2f_hi(xg.x) + b2f_hi(xr.x), acc[1]);
      acc[2] = fmaf(al, b2f_lo(xg.y) + b2f_lo(xr.y), acc[2]);
      acc[3] = fmaf(al, b2f_hi(xg.y) + b2f_hi(xr.y), acc[3]);
      acc[4] = fmaf(al, b2f_lo(xg.z) + b2f_lo(xr.z), acc[4]);
      acc[5] = fmaf(al, b2f_hi(xg.z) + b2f_hi(xr.z), acc[5]);
      acc[6] = fmaf(al, b2f_lo(xg.w) + b2f_lo(xr.w), acc[6]);
      acc[7] = fmaf(al, b2f_hi(xg.w) + b2f_hi(xr.w), acc[7]);
    }
  }
#pragma unroll
  for (int i = 0; i < 8; ++i){
    acc[i] += __shfl_xor(acc[i], 16, 64);
    acc[i] += __shfl_xor(acc[i], 32, 64);
  }
  if (g == 0){
    float4 v0 = make_float4(acc[0], acc[1], acc[2], acc[3]);
    float4 v1 = make_float4(acc[4], acc[5], acc[6], acc[7]);
    *reinterpret_cast<float4*>(agg + (size_t)o*DD + t*8)     = v0;
    *reinterpret_cast<float4*>(agg + (size_t)o*DD + t*8 + 4) = v1;
  }
}

// ---- FUSED: H = gru(x = LN(rrelu(AGG@Wh)), h = H), in place.
template<bool HAS_H>
__global__ void __launch_bounds__(256) k_whlngru(const float* __restrict__ AGG,
    float* H, const short* __restrict__ Bwh, const short* __restrict__ Bih,
    const short* __restrict__ Bhh, const float* __restrict__ lng,
    const float* __restrict__ lnb, const float* __restrict__ bih,
    const float* __restrict__ bhh, int rows){
  __shared__ short xtile[4 * 16 * XPAD];
  short* xl = xtile + (threadIdx.x >> 6) * 16 * XPAD;
  const int lane = threadIdx.x & 63;
  int wave = (int)((blockIdx.x * blockDim.x + threadIdx.x) >> 6);
  if (wave * 16 >= rows) return;
  int r0 = wave * 16;
  if (r0 + 16 > rows) r0 = rows - 16;
  r0 = __builtin_amdgcn_readfirstlane(r0);
  const int arow = lane & 15;
  const int koff = (lane >> 4) << 3;
  const int lrbase = (lane >> 4) << 2;

  short8 aa[4];
#pragma unroll
  for (int ks = 0; ks < 4; ++ks)
    aa[ks] = ld_frag_f32(AGG + (size_t)(r0 + arow) * DD + ks*32 + koff);
  f32x4 acc[8];
#pragma unroll
  for (int ct = 0; ct < 8; ++ct){
    acc[ct] = (f32x4)0.f;
#pragma unroll
    for (int ks = 0; ks < 4; ++ks){
      short8 bw = *reinterpret_cast<const short8*>(Bwh + ((size_t)(ct*4 + ks)*64 + lane)*8);
      acc[ct] = __builtin_amdgcn_mfma_f32_16x16x32_bf16(aa[ks], bw, acc[ct], 0, 0, 0);
    }
  }
#pragma unroll
  for (int ct = 0; ct < 8; ++ct)
#pragma unroll
    for (int reg = 0; reg < 4; ++reg) acc[ct][reg] = rrelu_f(acc[ct][reg]);

  float mu[4], rs[4];
#pragma unroll
  for (int reg = 0; reg < 4; ++reg){
    float s = 0.f, ss = 0.f;
#pragma unroll
    for (int ct = 0; ct < 8; ++ct){ float v = acc[ct][reg]; s += v; ss += v*v; }
    s = red16(s); ss = red16(ss);
    float m = s * (1.0f/128.0f);
    float var = ss * (1.0f/128.0f) - m*m;
    mu[reg] = m;
    rs[reg] = rsqrtf(var + LNEPS);
  }
#pragma unroll
  for (int ct = 0; ct < 8; ++ct){
    int col = ct*16 + (lane & 15);
    float gv = lng[col], bv = lnb[col];
#pragma unroll
    for (int reg = 0; reg < 4; ++reg){
      float xn = (acc[ct][reg] - mu[reg]) * rs[reg] * gv + bv;
      xl[(lrbase + reg) * XPAD + col] = bf16b(xn);
    }
  }

  short8 ax[4], ah8[4];
#pragma unroll
  for (int ks = 0; ks < 4; ++ks)
    ax[ks] = *reinterpret_cast<const short8*>(&xl[arow * XPAD + ks*32 + koff]);
  if (HAS_H){
#pragma unroll
    for (int ks = 0; ks < 4; ++ks)
      ah8[ks] = ld_frag_f32(H + (size_t)(r0 + arow) * DD + ks*32 + koff);
  }

#pragma unroll
  for (int ct = 0; ct < 8; ++ct){
    f32x4 air = (f32x4)0.f, aiz = (f32x4)0.f, ain = (f32x4)0.f;
    f32x4 ahr = (f32x4)0.f, ahz = (f32x4)0.f, ahn = (f32x4)0.f;
#pragma unroll
    for (int ks = 0; ks < 4; ++ks){
      short8 b0 = *reinterpret_cast<const short8*>(Bih + ((size_t)((0*8 + ct)*4 + ks)*64 + lane)*8);
      short8 b1 = *reinterpret_cast<const short8*>(Bih + ((size_t)((8 + ct)*4 + ks)*64 + lane)*8);
      short8 b2 = *reinterpret_cast<const short8*>(Bih + ((size_t)((16 + ct)*4 + ks)*64 + lane)*8);
      air = __builtin_amdgcn_mfma_f32_16x16x32_bf16(ax[ks], b0, air, 0, 0, 0);
      aiz = __builtin_amdgcn_mfma_f32_16x16x32_bf16(ax[ks], b1, aiz, 0, 0, 0);
      ain = __builtin_amdgcn_mfma_f32_16x16x32_bf16(ax[ks], b2, ain, 0, 0, 0);
      if (HAS_H){
        short8 c0 = *reinterpret_cast<const short8*>(Bhh + ((size_t)((0*8 + ct)*4 + ks)*64 + lane)*8);
        short8 c1 = *reinterpret_cast<const short8*>(Bhh + ((size_t)((8 + ct)*4 + ks)*64 + lane)*8);
        short8 c2 = *reinterpret_cast<const short8*>(Bhh + ((size_t)((16 + ct)*4 + ks)*64 + lane)*8);
        ahr = __builtin_amdgcn_mfma_f32_16x16x32_bf16(ah8[ks], c0, ahr, 0, 0, 0);
        ahz = __builtin_amdgcn_mfma_f32_16x16x32_bf16(ah8[ks], c1, ahz, 0, 0, 0);
        ahn = __builtin_amdgcn_mfma_f32_16x16x32_bf16(ah8[ks], c2, ahn, 0, 0, 0);
      }
    }
    int col = ct*16 + (lane & 15);
    float bi_r = bih[col], bi_z = bih[128 + col], bi_n = bih[256 + col];
    float bh_r = bhh[col], bh_z = bhh[128 + col], bh_n = bhh[256 + col];
#pragma unroll
    for (int reg = 0; reg < 4; ++reg){
      int row = r0 + lrbase + reg;
      float gi_r = air[reg] + bi_r;
      float gi_z = aiz[reg] + bi_z;
      float gi_n = ain[reg] + bi_n;
      float gh_r = (HAS_H ? ahr[reg] : 0.f) + bh_r;
      float gh_z = (HAS_H ? ahz[reg] : 0.f) + bh_z;
      float gh_n = (HAS_H ? ahn[reg] : 0.f) + bh_n;
      float rg = sigm(gi_r + gh_r);
      float zg = sigm(gi_z + gh_z);
      float ng = tanhf(gi_n + rg * gh_n);
      float hp = HAS_H ? H[(size_t)row * DD + col] : 0.f;
      H[(size_t)row * DD + col] = (1.f - zg) * ng + zg * hp;
    }
  }
}

// ---- scores = H @ wf ; record max-index winner per (batch,ent) slot
__global__ void __launch_bounds__(256) k_score(const float* __restrict__ Hf,
    const float* __restrict__ wf, const int* __restrict__ nb, const int* __restrict__ ne,
    float* __restrict__ scores, int* __restrict__ winner, int rows, int NENT){
  const int lane = threadIdx.x & 63;
  int wave = (int)((blockIdx.x * blockDim.x + threadIdx.x) >> 6);
  if (wave >= rows) return;
  int row = __builtin_amdgcn_readfirstlane(wave);
  float v = Hf[(size_t)row*DD + lane] * wf[lane] + Hf[(size_t)row*DD + 64 + lane] * wf[64 + lane];
  float s = wave_sum(v);
  if (lane == 0){
    scores[row] = s;
    int slot = nb[row] * NENT + ne[row];
    atomicMax(&winner[slot], row);
  }
}

__global__ void __launch_bounds__(256) k_scatter(const float* __restrict__ scores,
    const int* __restrict__ winner, const int* __restrict__ nb, const int* __restrict__ ne,
    float* __restrict__ out, int rows, int NENT){
  int n = blockIdx.x * blockDim.x + threadIdx.x;
  if (n < rows){
    int slot = nb[n] * NENT + ne[n];
    if (winner[slot] == n) out[slot] = scores[n];
  }
}

extern "C" void kernel_launch(void* const* d_in, const int* in_sizes, int n_in,
                              void* d_out, int out_size, void* d_ws, size_t ws_size,
                              hipStream_t stream){
  const float* hidden0 = (const float*)d_in[0];
  const float* rel0    = (const float*)d_in[1];
  const int* batch_idx = (const int*)d_in[2];
  const int* rel_i     = (const int*)d_in[3];
  const int* sub       = (const int*)d_in[4];
  const int* obj       = (const int*)d_in[5];
  const int* q_rel     = (const int*)d_in[6];
  const int* nb        = (const int*)d_in[7];
  const int* ne        = (const int*)d_in[8];
  const float* Ws      = (const float*)d_in[9];
  const float* Wr      = (const float*)d_in[10];
  const float* Wqr_w   = (const float*)d_in[11];
  const float* Wqr_b   = (const float*)d_in[12];
  const float* Wal_w   = (const float*)d_in[13];
  const float* Wal_b   = (const float*)d_in[14];
  const float* Wh      = (const float*)d_in[15];
  const float* rt_w    = (const float*)d_in[16];
  const float* rt_b    = (const float*)d_in[17];
  const float* ln_g    = (const float*)d_in[18];
  const float* ln_b    = (const float*)d_in[19];
  const float* lnr_g   = (const float*)d_in[20];
  const float* lnr_b   = (const float*)d_in[21];
  const float* wih     = (const float*)d_in[22];
  const float* whh     = (const float*)d_in[23];
  const float* bih     = (const float*)d_in[24];
  const float* bhh     = (const float*)d_in[25];
  const float* wfin    = (const float*)d_in[26];

  const int N    = in_sizes[0] / DD;
  const int NR   = in_sizes[1] / DD;
  const int E    = in_sizes[2];
  const int Bc   = in_sizes[6];
  const int L    = in_sizes[14];
  const int Rp1  = NR / Bc;
  const int NENT = out_size / Bc;

  char* wsp = (char*)d_ws;
  auto alloc = [&](size_t bytes) -> void* {
    void* p = (void*)wsp;
    wsp += (bytes + 255) & ~(size_t)255;
    return p;
  };
  float* AGG     = (float*)alloc((size_t)N * DD * 4);
  float* HBUF    = (float*)alloc((size_t)N * DD * 4);
  float* rel_cur = (float*)alloc((size_t)NR * DD * 4);
  unsigned short* GT = (unsigned short*)alloc((size_t)N * GTS * 2);
  unsigned short* RT = (unsigned short*)alloc((size_t)NR * GTS * 2);
  float* qr      = (float*)alloc((size_t)Bc * AA * 4);
  short* Bih     = (short*)alloc((size_t)(GG/16) * 4 * 64 * 8 * 2);
  short* Bhh     = (short*)alloc((size_t)(GG/16) * 4 * 64 * 8 * 2);
  short* Bws     = (short*)alloc((size_t)L * 4 * 4 * 64 * 8 * 2);
  short* Bwr     = (short*)alloc((size_t)L * 4 * 4 * 64 * 8 * 2);
  short* Bwh     = (short*)alloc((size_t)L * 8 * 4 * 64 * 8 * 2);
  float* scores  = (float*)alloc((size_t)N * 4);
  int*   winner  = (int*)alloc((size_t)Bc * NENT * 4);
  int*   deg     = (int*)alloc((size_t)N * 4);
  int*   row_st  = (int*)alloc((size_t)(N + 1) * 4);
  int*   cursor  = (int*)alloc((size_t)N * 4);
  int*   perm    = (int*)alloc((size_t)E * 4);
  int*   bsum    = (int*)alloc((size_t)1024 * 4);
  (void)ws_size; (void)n_in;

  hipMemcpyAsync(rel_cur, rel0, (size_t)NR * DD * 4, hipMemcpyDeviceToDevice, stream);
  {
    int totg = (GG/16) * 4 * 64;
    k_prep_bfrag<<<(totg + 255)/256, 256, 0, stream>>>(wih, Bih, GG);
    k_prep_bfrag<<<(totg + 255)/256, 256, 0, stream>>>(whh, Bhh, GG);
    int tot64 = 4 * 4 * 64;          // C=64 fragments
    int tot128 = 8 * 4 * 64;         // C=128 fragments
    for (int i = 0; i < L; ++i){
      k_prep_bfrag_km<<<(tot64 + 255)/256, 256, 0, stream>>>(Ws + (size_t)i*DD*AA, Bws + (size_t)i*tot64*8, AA, AA);
      k_prep_bfrag_km<<<(tot64 + 255)/256, 256, 0, stream>>>(Wr + (size_t)i*DD*AA, Bwr + (size_t)i*tot64*8, AA, AA);
      k_prep_bfrag_km<<<(tot128 + 255)/256, 256, 0, stream>>>(Wh + (size_t)i*DD*DD, Bwh + (size_t)i*tot128*8, DD, DD);
    }
  }
  hipMemsetAsync(d_out, 0, (size_t)out_size * 4, stream);
  hipMemsetAsync(winner, 0xFF, (size_t)Bc * NENT * 4, stream);

  // ---- build CSR over obj (edges constant across layers)
  hipMemsetAsync(deg, 0, (size_t)N * 4, stream);
  hipMemsetAsync(cursor, 0, (size_t)N * 4, stream);
  k_hist<<<(E + 255)/256, 256, 0, stream>>>(obj, deg, E);
  {
    int nb1 = (N + 1023)/1024;
    k_scan1<<<nb1, 1024, 0, stream>>>(deg, row_st, bsum, N);
    k_scan2<<<1, 1024, 0, stream>>>(bsum, nb1);
    k_scan3<<<(N + 255)/256, 256, 0, stream>>>(row_st, bsum, N, E);
  }
  k_scatter_edges<<<(E + 255)/256, 256, 0, stream>>>(obj, row_st, cursor, perm, E);

  const float* hid_in = hidden0;
  auto blocks4 = [](int waves){ return (waves + 3) / 4; };
  const int tot64 = 4 * 4 * 64;
  const int tot128 = 8 * 4 * 64;

  for (int i = 0; i < L; ++i){
    k_rel_transfer<<<blocks4(NR), 256, 0, stream>>>(rel_cur,
        rt_w + (size_t)i*DD*DD, rt_b + (size_t)i*DD,
        lnr_g + (size_t)i*DD, lnr_b + (size_t)i*DD, NR);
    k_proj_gt<<<blocks4((N+15)/16), 256, 0, stream>>>(hid_in, Bws + (size_t)i*tot64*8, GT, N);
    k_proj_gt<<<blocks4((NR+15)/16), 256, 0, stream>>>(rel_cur, Bwr + (size_t)i*tot64*8, RT, NR);
    k_projq<<<blocks4(Bc), 256, 0, stream>>>(rel_cur, Wqr_w + (size_t)i*DD*AA,
        Wqr_b + (size_t)i*AA, q_rel, qr, Bc, Rp1);
    k_edge_csr4<<<blocks4(N), 256, 0, stream>>>(GT, RT, qr,
        Wal_w + (size_t)i*AA, Wal_b + i,
        sub, batch_idx, rel_i, row_st, perm, AGG, N, Rp1);
    {
      int waves = (N + 15)/16;
      if (i == 0)
        k_whlngru<false><<<blocks4(waves), 256, 0, stream>>>(AGG, HBUF,
            Bwh + (size_t)i*tot128*8, Bih, Bhh,
            ln_g + (size_t)i*DD, ln_b + (size_t)i*DD, bih, bhh, N);
      else
        k_whlngru<true><<<blocks4(waves), 256, 0, stream>>>(AGG, HBUF,
            Bwh + (size_t)i*tot128*8, Bih, Bhh,
            ln_g + (size_t)i*DD, ln_b + (size_t)i*DD, bih, bhh, N);
    }
    k_ln_rows<<<blocks4(NR), 256, 0, stream>>>(rel_cur,
        lnr_g + (size_t)i*DD, lnr_b + (size_t)i*DD, NR);
    hid_in = HBUF;
  }

  k_score<<<blocks4(N), 256, 0, stream>>>(hid_in, wfin, nb, ne, scores, winner, N, NENT);
  k_scatter<<<(N + 255)/256, 256, 0, stream>>>(scores, winner, nb, ne, (float*)d_out, N, NENT);
}